// Round 14
// baseline (245.888 us; speedup 1.0000x reference)
//
#include <hip/hip_runtime.h>
#include <hip/hip_bf16.h>
#include <math.h>

#define BB 8
#define LL 160000
#define CC 4
#define NFFT 320
#define HOP 160
#define FB 161          // rfft bins
#define TT 1001         // frames
#define TP 1024         // padded frames per batch (t-slots) for STFT GEMM
#define RBLK 128        // stats blocks per batch
#define PI_D 3.14159265358979323846
#define NPAD 160320     // reflect-padded samples per (b,c): p in [-160, 160159]

#define CH 8            // scan t-chunk per thread
#define SCH 504         // scan outputs per half-block (2 halves cover 1001)

#define GM 16016        // irfft GEMM M = 2*BB*TT rows (beam,b,t)
#define KSEC 352        // irfft padded K per split-section (322 used)
#define LDK 704         // irfft A/Bt leading dim = 2 sections
#define KT 11           // irfft K-tiles of 32 per section
// NOTE: LDS row stride for bf16x8 tiles MUST keep rows 16B-aligned.
// stride 40 shorts = 80 B (aligned, ~2-way conflicts, cheap — R5: 61 us).
// stride 36 shorts = 72 B (misaligned b128 -> 3x slowdown — R9: 177 us). Do not repeat.
// LIFETIME NOTE (R13 bug): Bt/Bts must NOT live in the S region — k_gstft overwrites
// ALL of S. Both live in d_out's head (dead until k_ola fully overwrites at the end).

typedef __attribute__((ext_vector_type(8))) short bf16x8;
typedef __attribute__((ext_vector_type(4))) float f32x4;

__device__ __forceinline__ float2 cmulf(float2 a, float2 b){           // a*b
    return make_float2(a.x*b.x - a.y*b.y, a.x*b.y + a.y*b.x);
}
__device__ __forceinline__ float2 cmulcj(float2 a, float2 b){          // a*conj(b)
    return make_float2(a.x*b.x + a.y*b.y, a.y*b.x - a.x*b.y);
}
__device__ __forceinline__ float2 cjmul(float2 a, float2 b){           // conj(a)*b
    return make_float2(a.x*b.x + a.y*b.y, a.x*b.y - a.y*b.x);
}
__device__ __forceinline__ float2 csub(float2 a, float2 b){ return make_float2(a.x-b.x, a.y-b.y); }
__device__ __forceinline__ float2 cscale(float2 a, float s){ return make_float2(a.x*s, a.y*s); }
__device__ __forceinline__ float2 cdivf(float2 a, float2 b){           // a/b
    float inv = 1.0f/(b.x*b.x + b.y*b.y);
    return make_float2((a.x*b.x + a.y*b.y)*inv, (a.y*b.x - a.x*b.y)*inv);
}
__device__ __forceinline__ short bf_hi(float v){
    __hip_bfloat16 h = __float2bfloat16(v);
    short s; __builtin_memcpy(&s, &h, 2); return s;
}
__device__ __forceinline__ short bf_lo(float v){
    __hip_bfloat16 h = __float2bfloat16(v);
    float r = v - __bfloat162float(h);
    __hip_bfloat16 l = __float2bfloat16(r);
    short s; __builtin_memcpy(&s, &l, 2); return s;
}

// ---------- fused table generator: htab | Bts (STFT B) | Bt (irfft B) ----------
__global__ void k_gen(const float* __restrict__ win, float* __restrict__ htab,
                      short* __restrict__ Bts, short* __restrict__ Bt){
    int gid = blockIdx.x*256 + threadIdx.x;
    if (gid < 2*FB*CC){
        int i = gid;
        int c = i & 3;
        int k = (i >> 2) % FB;
        int m = i / (FB*CC);
        double coef = 2.0*PI_D*50.0*0.027*sin(40.0*PI_D/180.0)/340.0;
        double sgn = (m == 0) ? -1.0 : 1.0;
        double ph = sgn*coef*(double)k*(double)c;
        double s, c2;
        sincos(ph, &s, &c2);
        ((float2*)htab)[i] = make_float2((float)c2, (float)s);
        return;
    }
    gid -= 2*FB*CC;
    if (gid < 384*640){
        int col = gid / 640, kk = gid % 640;
        int n = (kk >= 320) ? kk - 320 : kk;
        int sec = (kk >= 320) ? 1 : 0;
        float v = 0.f;
        if (col < 2*FB){
            int k = col >> 1;
            double th = 2.0*PI_D*(double)k*(double)n/320.0;
            double s, co; sincos(th, &s, &co);
            double tw = (col & 1) ? -s : co;
            v = (float)((double)win[n]*tw);
        }
        Bts[gid] = sec ? bf_lo(v) : bf_hi(v);
        return;
    }
    gid -= 384*640;
    if (gid < NFFT*LDK){
        int n = gid / LDK, kk = gid % LDK;
        int sec = (kk >= KSEC) ? 1 : 0;
        int kk2 = kk - (sec ? KSEC : 0);
        float v = 0.f;
        if (kk2 < 2*FB){
            int bin = kk2 >> 1;
            double c = ((bin == 0 || bin == 160) ? 1.0 : 2.0) / 320.0;
            double th = 2.0*PI_D*(double)bin*(double)n/320.0;
            double s, co; sincos(th, &s, &co);
            v = (float)((kk2 & 1) ? -c*s : c*co);
        }
        Bt[(size_t)n*LDK + kk] = sec ? bf_lo(v) : bf_hi(v);
    }
}

// ---------- stage 1: per-(b,chunk) partial {sum4, min4, max4} ----------
__global__ __launch_bounds__(256) void k_stats1(const float* __restrict__ in, float* __restrict__ part){
    __shared__ float4 s4[256];
    __shared__ float4 mn4[256];
    __shared__ float4 mx4[256];
    int b = blockIdx.x / RBLK, chunk = blockIdx.x % RBLK;
    int tid = threadIdx.x;
    const float4* p = (const float4*)(in + (size_t)b*LL*CC);
    const int per = LL / RBLK;
    int start = chunk*per;
    float4 s  = make_float4(0.f,0.f,0.f,0.f);
    float4 mn = make_float4( 3.4e38f, 3.4e38f, 3.4e38f, 3.4e38f);
    float4 mx = make_float4(-3.4e38f,-3.4e38f,-3.4e38f,-3.4e38f);
    for (int i = start + tid; i < start + per; i += 256){
        float4 v = p[i];
        s.x += v.x; s.y += v.y; s.z += v.z; s.w += v.w;
        mn.x = fminf(mn.x, v.x); mn.y = fminf(mn.y, v.y); mn.z = fminf(mn.z, v.z); mn.w = fminf(mn.w, v.w);
        mx.x = fmaxf(mx.x, v.x); mx.y = fmaxf(mx.y, v.y); mx.z = fmaxf(mx.z, v.z); mx.w = fmaxf(mx.w, v.w);
    }
    s4[tid] = s; mn4[tid] = mn; mx4[tid] = mx;
    __syncthreads();
    for (int st = 128; st >= 1; st >>= 1){
        if (tid < st){
            float4 a = s4[tid], c = s4[tid+st];
            s4[tid] = make_float4(a.x+c.x, a.y+c.y, a.z+c.z, a.w+c.w);
            float4 d = mn4[tid], e = mn4[tid+st];
            mn4[tid] = make_float4(fminf(d.x,e.x), fminf(d.y,e.y), fminf(d.z,e.z), fminf(d.w,e.w));
            float4 f = mx4[tid], g = mx4[tid+st];
            mx4[tid] = make_float4(fmaxf(f.x,g.x), fmaxf(f.y,g.y), fmaxf(f.z,g.z), fmaxf(f.w,g.w));
        }
        __syncthreads();
    }
    if (tid == 0){
        float* dst = part + (size_t)(b*RBLK + chunk)*12;
        float4 a = s4[0], d = mn4[0], f = mx4[0];
        dst[0]=a.x; dst[1]=a.y; dst[2]=a.z; dst[3]=a.w;
        dst[4]=d.x; dst[5]=d.y; dst[6]=d.z; dst[7]=d.w;
        dst[8]=f.x; dst[9]=f.y; dst[10]=f.z; dst[11]=f.w;
    }
}

// ---------- stage 2: finalize mean + invmax per batch ----------
__global__ __launch_bounds__(128) void k_stats2(const float* __restrict__ part,
                                                float* __restrict__ mean, float* __restrict__ invmax){
    __shared__ float4 s4[128];
    __shared__ float4 mn4[128];
    __shared__ float4 mx4[128];
    int b = blockIdx.x, tid = threadIdx.x;
    const float* src = part + (size_t)(b*RBLK + tid)*12;
    s4[tid]  = make_float4(src[0], src[1], src[2], src[3]);
    mn4[tid] = make_float4(src[4], src[5], src[6], src[7]);
    mx4[tid] = make_float4(src[8], src[9], src[10], src[11]);
    __syncthreads();
    for (int st = 64; st >= 1; st >>= 1){
        if (tid < st){
            float4 a = s4[tid], c = s4[tid+st];
            s4[tid] = make_float4(a.x+c.x, a.y+c.y, a.z+c.z, a.w+c.w);
            float4 d = mn4[tid], e = mn4[tid+st];
            mn4[tid] = make_float4(fminf(d.x,e.x), fminf(d.y,e.y), fminf(d.z,e.z), fminf(d.w,e.w));
            float4 f = mx4[tid], g = mx4[tid+st];
            mx4[tid] = make_float4(fmaxf(f.x,g.x), fmaxf(f.y,g.y), fmaxf(f.z,g.z), fmaxf(f.w,g.w));
        }
        __syncthreads();
    }
    if (tid == 0){
        float4 sum = s4[0], mn = mn4[0], mx = mx4[0];
        float m0 = sum.x*(1.0f/LL), m1 = sum.y*(1.0f/LL), m2 = sum.z*(1.0f/LL), m3 = sum.w*(1.0f/LL);
        mean[b*4+0]=m0; mean[b*4+1]=m1; mean[b*4+2]=m2; mean[b*4+3]=m3;
        float a0 = fmaxf(mx.x - m0, m0 - mn.x);
        float a1 = fmaxf(mx.y - m1, m1 - mn.y);
        float a2 = fmaxf(mx.z - m2, m2 - mn.z);
        float a3 = fmaxf(mx.w - m3, m3 - mn.w);
        invmax[b] = 1.0f / fmaxf(fmaxf(a0, a1), fmaxf(a2, a3));
    }
}

// ---------- A-normalize: reflect-padded normalized bf16 hi/lo planes Ahi/Alo[b][c][NPAD] ----------
__global__ __launch_bounds__(256) void k_anorm(const float* __restrict__ in,
        const float* __restrict__ mean, const float* __restrict__ invmax,
        short* __restrict__ Ahi, short* __restrict__ Alo){
    int gid = blockIdx.x*256 + threadIdx.x;
    if (gid >= BB*CC*(NPAD/8)) return;
    int p8 = gid % (NPAD/8);
    int bc = gid / (NPAD/8);
    int b = bc >> 2;
    float mc = mean[bc];
    float iv = invmax[b];
    const float* px = in + (size_t)b*LL*CC + (bc & 3);
    bf16x8 h8, l8;
    #pragma unroll
    for (int j = 0; j < 8; ++j){
        int p = p8*8 + j - 160;
        int m2 = p < 0 ? -p : (p >= LL ? 2*LL - 2 - p : p);
        float v = (px[(size_t)m2*CC] - mc) * iv;
        __hip_bfloat16 h = __float2bfloat16(v);
        float r = v - __bfloat162float(h);
        __hip_bfloat16 l = __float2bfloat16(r);
        short hs, ls; __builtin_memcpy(&hs, &h, 2); __builtin_memcpy(&ls, &l, 2);
        h8[j] = hs; l8[j] = ls;
    }
    size_t o = (size_t)bc*NPAD + (size_t)p8*8;
    *(bf16x8*)&Ahi[o] = h8;
    *(bf16x8*)&Alo[o] = l8;
}

// ---------- STFT as MFMA GEMM (R5 structure, precomputed A planes): rows=(b,t,c), cols=(k,ri) ----------
// S out layout: complex S[b][k][t][c], c fastest (two float4 per (b,k,t))
__global__ __launch_bounds__(256) void k_gstft(const short* __restrict__ Ahi, const short* __restrict__ Alo,
        const short* __restrict__ Bts, float* __restrict__ S){
    __shared__ short stage[4*2560];          // Ah|Al|Bh|Bl, rows stride 40 shorts (80B, 16B-aligned)
    short* Ah = stage;
    short* Al = stage + 2560;
    short* Bh = stage + 5120;
    short* Bl = stage + 7680;
    float* Ct = (float*)stage;               // 64 x 66 floats (16.9 KB) overlays after K-loop
    int tid = threadIdx.x;
    int row0 = blockIdx.x*64;                // over b*TP*CC rows
    int col0 = blockIdx.y*64;
    int b  = row0 >> 12;                     // TP*CC = 4096 rows per batch
    int t0 = (row0 & 4095) >> 2;
    int tr = tid >> 2, tq = tid & 3, tk = tq*8;
    int tloc = t0 + (tr >> 2);
    int c    = tr & 3;
    bool vt  = tloc < TT;
    const short* pah = Ahi + (size_t)(b*4 + c)*NPAD;
    const short* pal = Alo + (size_t)(b*4 + c)*NPAD;
    int npbase = tloc*160;                   // p = tloc*HOP - HOP + n  ->  np = p + 160 = tloc*160 + n
    int wave = tid >> 6, lane = tid & 63;
    int wm = wave >> 1, wn = wave & 1;
    int l15 = lane & 15, quad = lane >> 4;
    f32x4 acc00 = {0.f,0.f,0.f,0.f}, acc01 = acc00, acc10 = acc00, acc11 = acc00;
    for (int kt = 0; kt < 10; ++kt){
        int k0 = kt*32;
        __syncthreads();
        bf16x8 hv = {}, lv = {};
        if (vt){
            hv = *(const bf16x8*)&pah[npbase + k0 + tk];
            lv = *(const bf16x8*)&pal[npbase + k0 + tk];
        }
        *(bf16x8*)&Ah[tr*40 + tk] = hv;
        *(bf16x8*)&Al[tr*40 + tk] = lv;
        const short* bp = Bts + (size_t)(col0 + tr)*640 + k0 + tk;
        *(bf16x8*)&Bh[tr*40 + tk] = *(const bf16x8*)bp;
        *(bf16x8*)&Bl[tr*40 + tk] = *(const bf16x8*)(bp + 320);
        __syncthreads();
        bf16x8 a0h = *(bf16x8*)&Ah[(wm*32 + l15)*40 + quad*8];
        bf16x8 a1h = *(bf16x8*)&Ah[(wm*32 + 16 + l15)*40 + quad*8];
        bf16x8 a0l = *(bf16x8*)&Al[(wm*32 + l15)*40 + quad*8];
        bf16x8 a1l = *(bf16x8*)&Al[(wm*32 + 16 + l15)*40 + quad*8];
        bf16x8 b0h = *(bf16x8*)&Bh[(wn*32 + l15)*40 + quad*8];
        bf16x8 b1h = *(bf16x8*)&Bh[(wn*32 + 16 + l15)*40 + quad*8];
        bf16x8 b0l = *(bf16x8*)&Bl[(wn*32 + l15)*40 + quad*8];
        bf16x8 b1l = *(bf16x8*)&Bl[(wn*32 + 16 + l15)*40 + quad*8];
        acc00 = __builtin_amdgcn_mfma_f32_16x16x32_bf16(a0h, b0h, acc00, 0, 0, 0);
        acc01 = __builtin_amdgcn_mfma_f32_16x16x32_bf16(a0h, b1h, acc01, 0, 0, 0);
        acc10 = __builtin_amdgcn_mfma_f32_16x16x32_bf16(a1h, b0h, acc10, 0, 0, 0);
        acc11 = __builtin_amdgcn_mfma_f32_16x16x32_bf16(a1h, b1h, acc11, 0, 0, 0);
        acc00 = __builtin_amdgcn_mfma_f32_16x16x32_bf16(a0l, b0h, acc00, 0, 0, 0);
        acc01 = __builtin_amdgcn_mfma_f32_16x16x32_bf16(a0l, b1h, acc01, 0, 0, 0);
        acc10 = __builtin_amdgcn_mfma_f32_16x16x32_bf16(a1l, b0h, acc10, 0, 0, 0);
        acc11 = __builtin_amdgcn_mfma_f32_16x16x32_bf16(a1l, b1h, acc11, 0, 0, 0);
        acc00 = __builtin_amdgcn_mfma_f32_16x16x32_bf16(a0h, b0l, acc00, 0, 0, 0);
        acc01 = __builtin_amdgcn_mfma_f32_16x16x32_bf16(a0h, b1l, acc01, 0, 0, 0);
        acc10 = __builtin_amdgcn_mfma_f32_16x16x32_bf16(a1h, b0l, acc10, 0, 0, 0);
        acc11 = __builtin_amdgcn_mfma_f32_16x16x32_bf16(a1h, b1l, acc11, 0, 0, 0);
    }
    // epilogue: LDS transpose, out in S layout
    __syncthreads();                       // staging reads done; Ct overlays
    #pragma unroll
    for (int r = 0; r < 4; ++r){
        int rl = wm*32 + quad*4 + r;       // channel = r (rl & 3 == r)
        Ct[rl*66 + wn*32 + l15]           = acc00[r];
        Ct[rl*66 + wn*32 + l15 + 16]      = acc01[r];
        Ct[(rl+16)*66 + wn*32 + l15]      = acc10[r];
        Ct[(rl+16)*66 + wn*32 + l15 + 16] = acc11[r];
    }
    __syncthreads();
    int tl = tid & 15, h = (tid >> 4) & 1, kq = tid >> 5;
    int t = t0 + tl;
    if (t < TT){
        float4* S4 = (float4*)S;
        for (int kk = kq; kk < 32; kk += 8){
            int kg = (col0 >> 1) + kk;
            if (kg < FB){
                float2 e0 = *(float2*)&Ct[(tl*4 + 2*h)*66 + 2*kk];
                float2 e1 = *(float2*)&Ct[(tl*4 + 2*h + 1)*66 + 2*kk];
                S4[((size_t)(b*FB + kg)*TT + t)*2 + h] = make_float4(e0.x, e0.y, e1.x, e1.y);
            }
        }
    }
}

// covariance recurrence update: R = a*R + wg*outer(X), a/wg handle first-frame
#define UPD(first) do{ \
    float aa = (first) ? 0.f : 0.05f; float wg = (first) ? 1.f : 0.95f; \
    float y0x=wg*x0.x, y0y=wg*x0.y, y1x=wg*x1.x, y1y=wg*x1.y; \
    float y2x=wg*x2.x, y2y=wg*x2.y, y3x=wg*x3.x, y3y=wg*x3.y; \
    d0 = aa*d0 + y0x*x0.x + y0y*x0.y; \
    d1 = aa*d1 + y1x*x1.x + y1y*x1.y; \
    d2 = aa*d2 + y2x*x2.x + y2y*x2.y; \
    d3 = aa*d3 + y3x*x3.x + y3y*x3.y; \
    r10.x = aa*r10.x + y1x*x0.x + y1y*x0.y;  r10.y = aa*r10.y + y1y*x0.x - y1x*x0.y; \
    r20.x = aa*r20.x + y2x*x0.x + y2y*x0.y;  r20.y = aa*r20.y + y2y*x0.x - y2x*x0.y; \
    r30.x = aa*r30.x + y3x*x0.x + y3y*x0.y;  r30.y = aa*r30.y + y3y*x0.x - y3x*x0.y; \
    r21.x = aa*r21.x + y2x*x1.x + y2y*x1.y;  r21.y = aa*r21.y + y2y*x1.x - y2x*x1.y; \
    r31.x = aa*r31.x + y3x*x1.x + y3y*x1.y;  r31.y = aa*r31.y + y3y*x1.x - y3x*x1.y; \
    r32.x = aa*r32.x + y3x*x2.x + y3y*x2.y;  r32.y = aa*r32.y + y3y*x2.x - y3x*x2.y; \
}while(0)

// ---------- LDS-staged chunked scan, half-strip; tile stages ONLY [tbase,te) (16,128 B < 16 KB) ----------
// Warm-up frames below tbase (threads 0,1 only) come straight from gmem.
// Division/sqrt-free Schur-adjugate solve (scale-invariance of s). S1/S2 layout: complex [b][f][t]
__global__ __launch_bounds__(64) void k_scan(const float* __restrict__ S, const float* __restrict__ htab,
                      float* __restrict__ S1, float* __restrict__ S2){
    __shared__ float4 tile[1008];     // 16,128 B: swizzled [tbase,te) strip; reused as output buffer
    int bid = blockIdx.x;
    int half = bid & 1;
    int bf = bid >> 1;                // b*FB + f
    int f  = bf % FB;
    int tid = threadIdx.x;
    int tbase = half*SCH;
    int te  = tbase + SCH; if (te > TT) te = TT;
    int nst = 2*(te - tbase);
    const float4* Sg = (const float4*)S + (size_t)bf*TT*2;
    const float4* Sp = Sg + (size_t)tbase*2;
    for (int i = tid; i < nst; i += 64)
        tile[i ^ ((i>>4)&7)] = Sp[i];                    // coalesced gmem read, swizzled LDS write
    __syncthreads();
    float2 out1[CH], out2[CH];
    int t0 = tbase + tid*CH;
    bool act = (tid*CH < SCH) && (t0 < TT);
    if (act){
        const float2* hp = (const float2*)htab;
        float2 ha0 = hp[f*4+0], ha1 = hp[f*4+1], ha2 = hp[f*4+2], ha3 = hp[f*4+3];
        float2 hb0 = hp[(FB+f)*4+0], hb1 = hp[(FB+f)*4+1], hb2 = hp[(FB+f)*4+2], hb3 = hp[(FB+f)*4+3];
        float d0=0,d1=0,d2=0,d3=0;
        float2 r10={0,0}, r20={0,0}, r30={0,0}, r21={0,0}, r31={0,0}, r32={0,0};
        int ts = t0 - 15; if (ts < 0) ts = 0;
        for (int tau = ts; tau < t0; ++tau){
            float4 v0, v1;
            if (tau >= tbase){
                int i0 = 2*(tau - tbase);
                v0 = tile[i0 ^ ((i0>>4)&7)];
                v1 = tile[(i0+1) ^ ((i0>>4)&7)];
            } else {
                v0 = Sg[2*tau];
                v1 = Sg[2*tau + 1];
            }
            float2 x0 = make_float2(v0.x, v0.y), x1 = make_float2(v0.z, v0.w);
            float2 x2 = make_float2(v1.x, v1.y), x3 = make_float2(v1.z, v1.w);
            UPD(tau == 0);
        }
        for (int j = 0; j < CH; ++j){
            int t = t0 + j;
            if (t >= TT) break;
            int i0 = 2*(t - tbase);
            float4 v0 = tile[i0 ^ ((i0>>4)&7)];
            float4 v1 = tile[(i0+1) ^ ((i0>>4)&7)];
            float2 x0 = make_float2(v0.x, v0.y), x1 = make_float2(v0.z, v0.w);
            float2 x2 = make_float2(v1.x, v1.y), x3 = make_float2(v1.z, v1.w);
            UPD(t == 0);
            float trc = d0 + d1 + d2 + d3;
            float lam = trc * 0.25f;
            float e0 = d0 + lam, e1 = d1 + lam, e2 = d2 + lam, e3 = d3 + lam;
            float detP = e0*e1 - (r10.x*r10.x + r10.y*r10.y);
            float2 w00 = csub(cscale(r20, e1), cmulf(r10, r21));
            float2 w01 = csub(cscale(r30, e1), cmulf(r10, r31));
            float2 w10 = csub(cscale(r21, e0), cjmul(r10, r20));
            float2 w11 = csub(cscale(r31, e0), cjmul(r10, r30));
            float2 va = cjmul(r30, w00), vb = cjmul(r31, w10);
            float2 V10 = make_float2(va.x + vb.x, -(va.y + vb.y));
            float reV00 = r20.x*w00.x + r20.y*w00.y + r21.x*w10.x + r21.y*w10.y;
            float reV11 = r30.x*w01.x + r30.y*w01.y + r31.x*w11.x + r31.y*w11.y;
            float t00 = detP*e2 - reV00;
            float t11 = detP*e3 - reV11;
            float2 t10 = csub(cscale(r32, detP), V10);
            float detT = t00*t11 - (t10.x*t10.x + t10.y*t10.y);
            #pragma unroll
            for (int m = 0; m < 2; ++m){
                float2 h0 = m ? hb0 : ha0;
                float2 h1 = m ? hb1 : ha1;
                float2 h2 = m ? hb2 : ha2;
                float2 h3 = m ? hb3 : ha3;
                float2 g0 = csub(cscale(h0, e1), cjmul(r10, h1));
                float2 g1 = csub(cscale(h1, e0), cmulf(r10, h0));
                float2 ta = cmulf(r20, g0), tb = cmulf(r21, g1);
                float2 hh0 = make_float2(detP*h2.x - ta.x - tb.x, detP*h2.y - ta.y - tb.y);
                ta = cmulf(r30, g0); tb = cmulf(r31, g1);
                float2 hh1 = make_float2(detP*h3.x - ta.x - tb.x, detP*h3.y - ta.y - tb.y);
                float2 y20 = csub(cscale(hh0, t11), cjmul(t10, hh1));
                float2 y21 = csub(cscale(hh1, t00), cmulf(t10, hh0));
                float2 u20 = cscale(y20, detP), u21 = cscale(y21, detP);
                ta = cmulcj(y20, r20); tb = cmulcj(y21, r30);
                float2 q0 = make_float2(detT*h0.x - ta.x - tb.x, detT*h0.y - ta.y - tb.y);
                ta = cmulcj(y20, r21); tb = cmulcj(y21, r31);
                float2 q1 = make_float2(detT*h1.x - ta.x - tb.x, detT*h1.y - ta.y - tb.y);
                float2 u10 = csub(cscale(q0, e1), cjmul(r10, q1));
                float2 u11 = csub(cscale(q1, e0), cmulf(r10, q0));
                float2 den = cjmul(h0, u10), tmp;
                tmp = cjmul(h1, u11); den.x += tmp.x; den.y += tmp.y;
                tmp = cjmul(h2, u20); den.x += tmp.x; den.y += tmp.y;
                tmp = cjmul(h3, u21); den.x += tmp.x; den.y += tmp.y;
                float2 num = cjmul(u10, x0);
                tmp = cjmul(u11, x1); num.x += tmp.x; num.y += tmp.y;
                tmp = cjmul(u20, x2); num.x += tmp.x; num.y += tmp.y;
                tmp = cjmul(u21, x3); num.x += tmp.x; num.y += tmp.y;
                float2 s = cdivf(num, make_float2(den.x, -den.y));
                if (m) out2[j] = s; else out1[j] = s;
            }
        }
    }
    __syncthreads();                      // all tile reads done -> reuse as output buffers
    float2* o1 = (float2*)tile;           // [0..511]
    float2* o2 = ((float2*)tile) + 528;   // [528..1039] (ends at float4 520 <= 1008)
    if (act){
        for (int j = 0; j < CH && t0 + j < TT; ++j){
            int lt = t0 - tbase + j;
            int iw = lt ^ ((lt>>3)&7);    // bank-spread write
            o1[iw] = out1[j];
            o2[iw] = out2[j];
        }
    }
    __syncthreads();
    int nout = te - tbase;
    float2* S1g = (float2*)S1 + (size_t)bf*TT + tbase;
    float2* S2g = (float2*)S2 + (size_t)bf*TT + tbase;
    for (int i = tid; i < nout; i += 64){
        int ir = i ^ ((i>>3)&7);
        S1g[i] = o1[ir];
        S2g[i] = o2[ir];
    }
}

// ---------- pack v2 (R8-verified): coalesced LDS transpose. block = (rb, 32-t tile) ----------
__global__ __launch_bounds__(256) void k_pack(const float* __restrict__ S1, const float* __restrict__ S2,
                                              short* __restrict__ A){
    __shared__ short tile[32*708];        // 45,312 B; row = t-in-tile, col = kk (hi 0..351 | lo 352..703)
    int bid = blockIdx.x;                 // rb*32 + tb
    int tb = bid & 31, rb = bid >> 5;
    int t0 = tb*32;
    int beam = rb >> 3, b = rb & 7;
    const float2* Sp = (const float2*)(beam ? S2 : S1) + (size_t)b*FB*TT;
    int tid = threadIdx.x;
    for (int idx = tid; idx < 32*176; idx += 256){
        int bin = idx >> 5, tq = idx & 31;
        int t = t0 + tq;
        float2 s = make_float2(0.f, 0.f);
        if (bin < FB && t < TT) s = Sp[(size_t)bin*TT + t];
        int c0 = 2*bin;
        tile[tq*708 + c0]            = bf_hi(s.x);
        tile[tq*708 + c0 + 1]        = bf_hi(s.y);
        tile[tq*708 + KSEC + c0]     = bf_lo(s.x);
        tile[tq*708 + KSEC + c0 + 1] = bf_lo(s.y);
    }
    __syncthreads();
    for (int idx = tid; idx < 32*176; idx += 256){
        int tq = idx / 176, k4 = idx % 176;
        int t = t0 + tq;
        if (t < TT)
            *(short4*)&A[(size_t)(rb*TT + t)*LDK + k4*4] = *(short4*)&tile[tq*708 + k4*4];
    }
}

// ---------- irfft MFMA GEMM: frames[GM,320] = 3-segment bf16 split product ----------
__global__ __launch_bounds__(256) void k_gemm(const short* __restrict__ A, const short* __restrict__ Bt,
                                              float* __restrict__ C){
    __shared__ short As[64*40];
    __shared__ short Bs[64*40];
    int tid = threadIdx.x;
    int row0 = blockIdx.x * 64;
    int col0 = blockIdx.y * 64;
    int wave = tid >> 6, lane = tid & 63;
    int wm = wave >> 1, wn = wave & 1;
    int l15 = lane & 15, quad = lane >> 4;
    f32x4 acc00 = {0.f,0.f,0.f,0.f}, acc01 = acc00, acc10 = acc00, acc11 = acc00;
    int tr = tid >> 2;
    int tk = (tid & 3) * 8;
    int gr = row0 + tr;
    bool rok = gr < GM;
    const size_t arow = (size_t)gr*LDK;
    const size_t brow = (size_t)(col0 + tr)*LDK;
    for (int seg = 0; seg < 3; ++seg){
        int aofs = (seg == 1) ? KSEC : 0;
        int bofs = (seg == 2) ? KSEC : 0;
        for (int kt = 0; kt < KT; ++kt){
            int k0 = kt*32;
            __syncthreads();
            bf16x8 av = {};
            if (rok) av = *(const bf16x8*)&A[arow + aofs + k0 + tk];
            bf16x8 bv = *(const bf16x8*)&Bt[brow + bofs + k0 + tk];
            *(bf16x8*)&As[tr*40 + tk] = av;
            *(bf16x8*)&Bs[tr*40 + tk] = bv;
            __syncthreads();
            bf16x8 a0 = *(bf16x8*)&As[(wm*32 + l15)*40 + quad*8];
            bf16x8 a1 = *(bf16x8*)&As[(wm*32 + 16 + l15)*40 + quad*8];
            bf16x8 b0 = *(bf16x8*)&Bs[(wn*32 + l15)*40 + quad*8];
            bf16x8 b1 = *(bf16x8*)&Bs[(wn*32 + 16 + l15)*40 + quad*8];
            acc00 = __builtin_amdgcn_mfma_f32_16x16x32_bf16(a0, b0, acc00, 0, 0, 0);
            acc01 = __builtin_amdgcn_mfma_f32_16x16x32_bf16(a0, b1, acc01, 0, 0, 0);
            acc10 = __builtin_amdgcn_mfma_f32_16x16x32_bf16(a1, b0, acc10, 0, 0, 0);
            acc11 = __builtin_amdgcn_mfma_f32_16x16x32_bf16(a1, b1, acc11, 0, 0, 0);
        }
    }
    for (int r = 0; r < 4; ++r){
        int orow0 = row0 + wm*32 + quad*4 + r;
        int ocol0 = col0 + wn*32 + l15;
        if (orow0 < GM){
            C[(size_t)orow0*NFFT + ocol0]      = acc00[r];
            C[(size_t)orow0*NFFT + ocol0 + 16] = acc01[r];
        }
        if (orow0 + 16 < GM){
            C[(size_t)(orow0+16)*NFFT + ocol0]      = acc10[r];
            C[(size_t)(orow0+16)*NFFT + ocol0 + 16] = acc11[r];
        }
    }
}

// ---------- overlap-add, float4: 4 outputs/thread (wsum==2 in cropped interior) ----------
__global__ __launch_bounds__(256) void k_ola(const float* __restrict__ frames, float* __restrict__ out){
    int gid = blockIdx.x*256 + threadIdx.x;
    if (gid >= 2*BB*(LL/4)) return;
    int o4 = (gid % (LL/4))*4;
    int rb = gid / (LL/4);                 // beam*BB + b
    int i  = o4 + HOP;                     // mult of 4; r in {0,4,...,156}
    int t1 = i / HOP;
    int r  = i - t1*HOP;
    const float4* fb = (const float4*)(frames + (size_t)rb*TT*NFFT);
    float4 a = fb[(t1*NFFT + r) >> 2];
    float4 b = fb[((t1-1)*NFFT + r + HOP) >> 2];
    ((float4*)out)[gid] = make_float4(0.5f*(a.x+b.x), 0.5f*(a.y+b.y), 0.5f*(a.z+b.z), 0.5f*(a.w+b.w));
}

extern "C" void kernel_launch(void* const* d_in, const int* in_sizes, int n_in,
                              void* d_out, int out_size, void* d_ws, size_t ws_size,
                              hipStream_t stream){
    const float* in  = (const float*)d_in[0];   // [B, L, C] fp32
    const float* win = (const float*)d_in[1];   // [320] fp32
    float* ws = (float*)d_ws;
    // ws (floats): mean 32 | invmax 8 | htab 2576 | pad -> header 3072
    //              | S1 (2,578,576) | S2 (2,578,576) | S (10,314,304)   total ~62 MB
    // aliases: part -> S1 head (dead before k_anorm); Ahi/Alo -> S1+S2 (dead after k_gstft);
    //          Bts + Bt -> head of d_out (dead until k_ola fully overwrites; NOT in S — R13 bug);
    //          A_ir -> S (post-scan); frames -> S1/S2 (post-pack)
    float* mean   = ws;
    float* invmax = ws + 32;
    float* htab   = ws + 48;
    float* S1     = ws + 3072;
    size_t nS1 = (size_t)2*BB*FB*TT;            // 2,578,576 floats
    float* S2 = S1 + nS1;
    float* S  = S2 + nS1;                       // 10,314,304 floats
    float* part = S1;
    short* Ahi = (short*)S1;                    // 8*4*160320 = 5,130,240 shorts
    short* Alo = Ahi + (size_t)BB*CC*NPAD;      // total 10,260,480 shorts <= S1+S2 (10,314,304 short-equiv)
    short* Bts = (short*)d_out;                 // 245,760 shorts (= 122,880 floats)
    short* Bt  = (short*)((float*)d_out + 131072); // 225,280 shorts at float-offset 131072 (16B aligned)
    short* A  = (short*)S;                      // irfft A: 16016*704 bf16
    float* frames = S1;                         // 16016*320 floats over dead S1+S2

    int ngen = 2*FB*CC + 384*640 + NFFT*LDK;    // fused table generation
    k_gen<<<dim3((ngen + 255)/256), dim3(256), 0, stream>>>(win, htab, Bts, Bt);
    k_stats1<<<dim3(BB*RBLK), dim3(256), 0, stream>>>(in, part);
    k_stats2<<<dim3(BB), dim3(128), 0, stream>>>(part, mean, invmax);
    k_anorm<<<dim3((BB*CC*(NPAD/8) + 255)/256), dim3(256), 0, stream>>>(in, mean, invmax, Ahi, Alo);
    k_gstft<<<dim3(BB*TP*CC/64, 6), dim3(256), 0, stream>>>(Ahi, Alo, Bts, S);
    k_scan<<<dim3(2*BB*FB), dim3(64), 0, stream>>>(S, htab, S1, S2);
    k_pack<<<dim3(512), dim3(256), 0, stream>>>(S1, S2, A);
    k_gemm<<<dim3((GM + 63)/64, NFFT/64), dim3(256), 0, stream>>>(A, Bt, frames);
    k_ola<<<dim3((2*BB*(LL/4) + 255)/256), dim3(256), 0, stream>>>(frames, (float*)d_out);
}

// Round 15
// 236.713 us; speedup vs baseline: 1.0388x; 1.0388x over previous
//
#include <hip/hip_runtime.h>
#include <hip/hip_bf16.h>
#include <math.h>

#define BB 8
#define LL 160000
#define CC 4
#define NFFT 320
#define HOP 160
#define FB 161          // rfft bins
#define TT 1001         // frames
#define TP 1024         // padded frames per batch (t-slots) for STFT GEMM
#define RBLK 128        // stats blocks per batch
#define PI_D 3.14159265358979323846
#define NPAD 160320     // reflect-padded samples per (b,c): p in [-160, 160159]

#define CH 4            // scan t-chunk per thread (CH=4 + 128-thread blocks: 2x waves vs R14)
#define SCH 504         // scan outputs per half-block (2 halves cover 1001)

#define GM 16016        // irfft GEMM M = 2*BB*TT rows (beam,b,t)
#define KSEC 352        // irfft padded K per split-section (322 used)
#define LDK 704         // irfft A/Bt leading dim = 2 sections
#define KT 11           // irfft K-tiles of 32 per section
// NOTE: LDS row stride for bf16x8 tiles MUST keep rows 16B-aligned.
// stride 40 shorts = 80 B (aligned, ~2-way conflicts, cheap — R5: 61 us).
// stride 36 shorts = 72 B (misaligned b128 -> 3x slowdown — R9: 177 us). Do not repeat.
// LIFETIME NOTE (R13 bug): Bt/Bts must NOT live in the S region — k_gstft overwrites
// ALL of S. Both live in d_out's head (dead until k_ola fully overwrites at the end).

typedef __attribute__((ext_vector_type(8))) short bf16x8;
typedef __attribute__((ext_vector_type(4))) float f32x4;

__device__ __forceinline__ float2 cmulf(float2 a, float2 b){           // a*b
    return make_float2(a.x*b.x - a.y*b.y, a.x*b.y + a.y*b.x);
}
__device__ __forceinline__ float2 cmulcj(float2 a, float2 b){          // a*conj(b)
    return make_float2(a.x*b.x + a.y*b.y, a.y*b.x - a.x*b.y);
}
__device__ __forceinline__ float2 cjmul(float2 a, float2 b){           // conj(a)*b
    return make_float2(a.x*b.x + a.y*b.y, a.x*b.y - a.y*b.x);
}
__device__ __forceinline__ float2 csub(float2 a, float2 b){ return make_float2(a.x-b.x, a.y-b.y); }
__device__ __forceinline__ float2 cscale(float2 a, float s){ return make_float2(a.x*s, a.y*s); }
__device__ __forceinline__ float2 cdivf(float2 a, float2 b){           // a/b
    float inv = 1.0f/(b.x*b.x + b.y*b.y);
    return make_float2((a.x*b.x + a.y*b.y)*inv, (a.y*b.x - a.x*b.y)*inv);
}
__device__ __forceinline__ short bf_hi(float v){
    __hip_bfloat16 h = __float2bfloat16(v);
    short s; __builtin_memcpy(&s, &h, 2); return s;
}
__device__ __forceinline__ short bf_lo(float v){
    __hip_bfloat16 h = __float2bfloat16(v);
    float r = v - __bfloat162float(h);
    __hip_bfloat16 l = __float2bfloat16(r);
    short s; __builtin_memcpy(&s, &l, 2); return s;
}

// ---------- fused table generator: htab | Bts (STFT B) | Bt (irfft B) ----------
__global__ void k_gen(const float* __restrict__ win, float* __restrict__ htab,
                      short* __restrict__ Bts, short* __restrict__ Bt){
    int gid = blockIdx.x*256 + threadIdx.x;
    if (gid < 2*FB*CC){
        int i = gid;
        int c = i & 3;
        int k = (i >> 2) % FB;
        int m = i / (FB*CC);
        double coef = 2.0*PI_D*50.0*0.027*sin(40.0*PI_D/180.0)/340.0;
        double sgn = (m == 0) ? -1.0 : 1.0;
        double ph = sgn*coef*(double)k*(double)c;
        double s, c2;
        sincos(ph, &s, &c2);
        ((float2*)htab)[i] = make_float2((float)c2, (float)s);
        return;
    }
    gid -= 2*FB*CC;
    if (gid < 384*640){
        int col = gid / 640, kk = gid % 640;
        int n = (kk >= 320) ? kk - 320 : kk;
        int sec = (kk >= 320) ? 1 : 0;
        float v = 0.f;
        if (col < 2*FB){
            int k = col >> 1;
            double th = 2.0*PI_D*(double)k*(double)n/320.0;
            double s, co; sincos(th, &s, &co);
            double tw = (col & 1) ? -s : co;
            v = (float)((double)win[n]*tw);
        }
        Bts[gid] = sec ? bf_lo(v) : bf_hi(v);
        return;
    }
    gid -= 384*640;
    if (gid < NFFT*LDK){
        int n = gid / LDK, kk = gid % LDK;
        int sec = (kk >= KSEC) ? 1 : 0;
        int kk2 = kk - (sec ? KSEC : 0);
        float v = 0.f;
        if (kk2 < 2*FB){
            int bin = kk2 >> 1;
            double c = ((bin == 0 || bin == 160) ? 1.0 : 2.0) / 320.0;
            double th = 2.0*PI_D*(double)bin*(double)n/320.0;
            double s, co; sincos(th, &s, &co);
            v = (float)((kk2 & 1) ? -c*s : c*co);
        }
        Bt[(size_t)n*LDK + kk] = sec ? bf_lo(v) : bf_hi(v);
    }
}

// ---------- stage 1: per-(b,chunk) partial {sum4, min4, max4} ----------
__global__ __launch_bounds__(256) void k_stats1(const float* __restrict__ in, float* __restrict__ part){
    __shared__ float4 s4[256];
    __shared__ float4 mn4[256];
    __shared__ float4 mx4[256];
    int b = blockIdx.x / RBLK, chunk = blockIdx.x % RBLK;
    int tid = threadIdx.x;
    const float4* p = (const float4*)(in + (size_t)b*LL*CC);
    const int per = LL / RBLK;
    int start = chunk*per;
    float4 s  = make_float4(0.f,0.f,0.f,0.f);
    float4 mn = make_float4( 3.4e38f, 3.4e38f, 3.4e38f, 3.4e38f);
    float4 mx = make_float4(-3.4e38f,-3.4e38f,-3.4e38f,-3.4e38f);
    for (int i = start + tid; i < start + per; i += 256){
        float4 v = p[i];
        s.x += v.x; s.y += v.y; s.z += v.z; s.w += v.w;
        mn.x = fminf(mn.x, v.x); mn.y = fminf(mn.y, v.y); mn.z = fminf(mn.z, v.z); mn.w = fminf(mn.w, v.w);
        mx.x = fmaxf(mx.x, v.x); mx.y = fmaxf(mx.y, v.y); mx.z = fmaxf(mx.z, v.z); mx.w = fmaxf(mx.w, v.w);
    }
    s4[tid] = s; mn4[tid] = mn; mx4[tid] = mx;
    __syncthreads();
    for (int st = 128; st >= 1; st >>= 1){
        if (tid < st){
            float4 a = s4[tid], c = s4[tid+st];
            s4[tid] = make_float4(a.x+c.x, a.y+c.y, a.z+c.z, a.w+c.w);
            float4 d = mn4[tid], e = mn4[tid+st];
            mn4[tid] = make_float4(fminf(d.x,e.x), fminf(d.y,e.y), fminf(d.z,e.z), fminf(d.w,e.w));
            float4 f = mx4[tid], g = mx4[tid+st];
            mx4[tid] = make_float4(fmaxf(f.x,g.x), fmaxf(f.y,g.y), fmaxf(f.z,g.z), fmaxf(f.w,g.w));
        }
        __syncthreads();
    }
    if (tid == 0){
        float* dst = part + (size_t)(b*RBLK + chunk)*12;
        float4 a = s4[0], d = mn4[0], f = mx4[0];
        dst[0]=a.x; dst[1]=a.y; dst[2]=a.z; dst[3]=a.w;
        dst[4]=d.x; dst[5]=d.y; dst[6]=d.z; dst[7]=d.w;
        dst[8]=f.x; dst[9]=f.y; dst[10]=f.z; dst[11]=f.w;
    }
}

// ---------- stage 2: finalize mean + invmax per batch ----------
__global__ __launch_bounds__(128) void k_stats2(const float* __restrict__ part,
                                                float* __restrict__ mean, float* __restrict__ invmax){
    __shared__ float4 s4[128];
    __shared__ float4 mn4[128];
    __shared__ float4 mx4[128];
    int b = blockIdx.x, tid = threadIdx.x;
    const float* src = part + (size_t)(b*RBLK + tid)*12;
    s4[tid]  = make_float4(src[0], src[1], src[2], src[3]);
    mn4[tid] = make_float4(src[4], src[5], src[6], src[7]);
    mx4[tid] = make_float4(src[8], src[9], src[10], src[11]);
    __syncthreads();
    for (int st = 64; st >= 1; st >>= 1){
        if (tid < st){
            float4 a = s4[tid], c = s4[tid+st];
            s4[tid] = make_float4(a.x+c.x, a.y+c.y, a.z+c.z, a.w+c.w);
            float4 d = mn4[tid], e = mn4[tid+st];
            mn4[tid] = make_float4(fminf(d.x,e.x), fminf(d.y,e.y), fminf(d.z,e.z), fminf(d.w,e.w));
            float4 f = mx4[tid], g = mx4[tid+st];
            mx4[tid] = make_float4(fmaxf(f.x,g.x), fmaxf(f.y,g.y), fmaxf(f.z,g.z), fmaxf(f.w,g.w));
        }
        __syncthreads();
    }
    if (tid == 0){
        float4 sum = s4[0], mn = mn4[0], mx = mx4[0];
        float m0 = sum.x*(1.0f/LL), m1 = sum.y*(1.0f/LL), m2 = sum.z*(1.0f/LL), m3 = sum.w*(1.0f/LL);
        mean[b*4+0]=m0; mean[b*4+1]=m1; mean[b*4+2]=m2; mean[b*4+3]=m3;
        float a0 = fmaxf(mx.x - m0, m0 - mn.x);
        float a1 = fmaxf(mx.y - m1, m1 - mn.y);
        float a2 = fmaxf(mx.z - m2, m2 - mn.z);
        float a3 = fmaxf(mx.w - m3, m3 - mn.w);
        invmax[b] = 1.0f / fmaxf(fmaxf(a0, a1), fmaxf(a2, a3));
    }
}

// ---------- A-normalize: reflect-padded normalized bf16 hi/lo planes Ahi/Alo[b][c][NPAD] ----------
__global__ __launch_bounds__(256) void k_anorm(const float* __restrict__ in,
        const float* __restrict__ mean, const float* __restrict__ invmax,
        short* __restrict__ Ahi, short* __restrict__ Alo){
    int gid = blockIdx.x*256 + threadIdx.x;
    if (gid >= BB*CC*(NPAD/8)) return;
    int p8 = gid % (NPAD/8);
    int bc = gid / (NPAD/8);
    int b = bc >> 2;
    float mc = mean[bc];
    float iv = invmax[b];
    const float* px = in + (size_t)b*LL*CC + (bc & 3);
    bf16x8 h8, l8;
    #pragma unroll
    for (int j = 0; j < 8; ++j){
        int p = p8*8 + j - 160;
        int m2 = p < 0 ? -p : (p >= LL ? 2*LL - 2 - p : p);
        float v = (px[(size_t)m2*CC] - mc) * iv;
        __hip_bfloat16 h = __float2bfloat16(v);
        float r = v - __bfloat162float(h);
        __hip_bfloat16 l = __float2bfloat16(r);
        short hs, ls; __builtin_memcpy(&hs, &h, 2); __builtin_memcpy(&ls, &l, 2);
        h8[j] = hs; l8[j] = ls;
    }
    size_t o = (size_t)bc*NPAD + (size_t)p8*8;
    *(bf16x8*)&Ahi[o] = h8;
    *(bf16x8*)&Alo[o] = l8;
}

// ---------- STFT as MFMA GEMM (R5 structure, precomputed A planes): rows=(b,t,c), cols=(k,ri) ----------
// S out layout: complex S[b][k][t][c], c fastest (two float4 per (b,k,t))
__global__ __launch_bounds__(256) void k_gstft(const short* __restrict__ Ahi, const short* __restrict__ Alo,
        const short* __restrict__ Bts, float* __restrict__ S){
    __shared__ short stage[4*2560];          // Ah|Al|Bh|Bl, rows stride 40 shorts (80B, 16B-aligned)
    short* Ah = stage;
    short* Al = stage + 2560;
    short* Bh = stage + 5120;
    short* Bl = stage + 7680;
    float* Ct = (float*)stage;               // 64 x 66 floats (16.9 KB) overlays after K-loop
    int tid = threadIdx.x;
    int row0 = blockIdx.x*64;                // over b*TP*CC rows
    int col0 = blockIdx.y*64;
    int b  = row0 >> 12;                     // TP*CC = 4096 rows per batch
    int t0 = (row0 & 4095) >> 2;
    int tr = tid >> 2, tq = tid & 3, tk = tq*8;
    int tloc = t0 + (tr >> 2);
    int c    = tr & 3;
    bool vt  = tloc < TT;
    const short* pah = Ahi + (size_t)(b*4 + c)*NPAD;
    const short* pal = Alo + (size_t)(b*4 + c)*NPAD;
    int npbase = tloc*160;                   // p = tloc*HOP - HOP + n  ->  np = p + 160 = tloc*160 + n
    int wave = tid >> 6, lane = tid & 63;
    int wm = wave >> 1, wn = wave & 1;
    int l15 = lane & 15, quad = lane >> 4;
    f32x4 acc00 = {0.f,0.f,0.f,0.f}, acc01 = acc00, acc10 = acc00, acc11 = acc00;
    for (int kt = 0; kt < 10; ++kt){
        int k0 = kt*32;
        __syncthreads();
        bf16x8 hv = {}, lv = {};
        if (vt){
            hv = *(const bf16x8*)&pah[npbase + k0 + tk];
            lv = *(const bf16x8*)&pal[npbase + k0 + tk];
        }
        *(bf16x8*)&Ah[tr*40 + tk] = hv;
        *(bf16x8*)&Al[tr*40 + tk] = lv;
        const short* bp = Bts + (size_t)(col0 + tr)*640 + k0 + tk;
        *(bf16x8*)&Bh[tr*40 + tk] = *(const bf16x8*)bp;
        *(bf16x8*)&Bl[tr*40 + tk] = *(const bf16x8*)(bp + 320);
        __syncthreads();
        bf16x8 a0h = *(bf16x8*)&Ah[(wm*32 + l15)*40 + quad*8];
        bf16x8 a1h = *(bf16x8*)&Ah[(wm*32 + 16 + l15)*40 + quad*8];
        bf16x8 a0l = *(bf16x8*)&Al[(wm*32 + l15)*40 + quad*8];
        bf16x8 a1l = *(bf16x8*)&Al[(wm*32 + 16 + l15)*40 + quad*8];
        bf16x8 b0h = *(bf16x8*)&Bh[(wn*32 + l15)*40 + quad*8];
        bf16x8 b1h = *(bf16x8*)&Bh[(wn*32 + 16 + l15)*40 + quad*8];
        bf16x8 b0l = *(bf16x8*)&Bl[(wn*32 + l15)*40 + quad*8];
        bf16x8 b1l = *(bf16x8*)&Bl[(wn*32 + 16 + l15)*40 + quad*8];
        acc00 = __builtin_amdgcn_mfma_f32_16x16x32_bf16(a0h, b0h, acc00, 0, 0, 0);
        acc01 = __builtin_amdgcn_mfma_f32_16x16x32_bf16(a0h, b1h, acc01, 0, 0, 0);
        acc10 = __builtin_amdgcn_mfma_f32_16x16x32_bf16(a1h, b0h, acc10, 0, 0, 0);
        acc11 = __builtin_amdgcn_mfma_f32_16x16x32_bf16(a1h, b1h, acc11, 0, 0, 0);
        acc00 = __builtin_amdgcn_mfma_f32_16x16x32_bf16(a0l, b0h, acc00, 0, 0, 0);
        acc01 = __builtin_amdgcn_mfma_f32_16x16x32_bf16(a0l, b1h, acc01, 0, 0, 0);
        acc10 = __builtin_amdgcn_mfma_f32_16x16x32_bf16(a1l, b0h, acc10, 0, 0, 0);
        acc11 = __builtin_amdgcn_mfma_f32_16x16x32_bf16(a1l, b1h, acc11, 0, 0, 0);
        acc00 = __builtin_amdgcn_mfma_f32_16x16x32_bf16(a0h, b0l, acc00, 0, 0, 0);
        acc01 = __builtin_amdgcn_mfma_f32_16x16x32_bf16(a0h, b1l, acc01, 0, 0, 0);
        acc10 = __builtin_amdgcn_mfma_f32_16x16x32_bf16(a1h, b0l, acc10, 0, 0, 0);
        acc11 = __builtin_amdgcn_mfma_f32_16x16x32_bf16(a1h, b1l, acc11, 0, 0, 0);
    }
    // epilogue: LDS transpose, out in S layout
    __syncthreads();                       // staging reads done; Ct overlays
    #pragma unroll
    for (int r = 0; r < 4; ++r){
        int rl = wm*32 + quad*4 + r;       // channel = r (rl & 3 == r)
        Ct[rl*66 + wn*32 + l15]           = acc00[r];
        Ct[rl*66 + wn*32 + l15 + 16]      = acc01[r];
        Ct[(rl+16)*66 + wn*32 + l15]      = acc10[r];
        Ct[(rl+16)*66 + wn*32 + l15 + 16] = acc11[r];
    }
    __syncthreads();
    int tl = tid & 15, h = (tid >> 4) & 1, kq = tid >> 5;
    int t = t0 + tl;
    if (t < TT){
        float4* S4 = (float4*)S;
        for (int kk = kq; kk < 32; kk += 8){
            int kg = (col0 >> 1) + kk;
            if (kg < FB){
                float2 e0 = *(float2*)&Ct[(tl*4 + 2*h)*66 + 2*kk];
                float2 e1 = *(float2*)&Ct[(tl*4 + 2*h + 1)*66 + 2*kk];
                S4[((size_t)(b*FB + kg)*TT + t)*2 + h] = make_float4(e0.x, e0.y, e1.x, e1.y);
            }
        }
    }
}

// covariance recurrence update: R = a*R + wg*outer(X), a/wg handle first-frame
#define UPD(first) do{ \
    float aa = (first) ? 0.f : 0.05f; float wg = (first) ? 1.f : 0.95f; \
    float y0x=wg*x0.x, y0y=wg*x0.y, y1x=wg*x1.x, y1y=wg*x1.y; \
    float y2x=wg*x2.x, y2y=wg*x2.y, y3x=wg*x3.x, y3y=wg*x3.y; \
    d0 = aa*d0 + y0x*x0.x + y0y*x0.y; \
    d1 = aa*d1 + y1x*x1.x + y1y*x1.y; \
    d2 = aa*d2 + y2x*x2.x + y2y*x2.y; \
    d3 = aa*d3 + y3x*x3.x + y3y*x3.y; \
    r10.x = aa*r10.x + y1x*x0.x + y1y*x0.y;  r10.y = aa*r10.y + y1y*x0.x - y1x*x0.y; \
    r20.x = aa*r20.x + y2x*x0.x + y2y*x0.y;  r20.y = aa*r20.y + y2y*x0.x - y2x*x0.y; \
    r30.x = aa*r30.x + y3x*x0.x + y3y*x0.y;  r30.y = aa*r30.y + y3y*x0.x - y3x*x0.y; \
    r21.x = aa*r21.x + y2x*x1.x + y2y*x1.y;  r21.y = aa*r21.y + y2y*x1.x - y2x*x1.y; \
    r31.x = aa*r31.x + y3x*x1.x + y3y*x1.y;  r31.y = aa*r31.y + y3y*x1.x - y3x*x1.y; \
    r32.x = aa*r32.x + y3x*x2.x + y3y*x2.y;  r32.y = aa*r32.y + y3y*x2.x - y3x*x2.y; \
}while(0)

// ---------- LDS-staged chunked scan, half-strip, CH=4 x 128 threads (2x waves vs CH=8/64t) ----------
// Warm-up frames below tbase (threads 0..3) come straight from gmem.
// Division/sqrt-free Schur-adjugate solve (scale-invariance of s). S1/S2 layout: complex [b][f][t]
__global__ __launch_bounds__(128) void k_scan(const float* __restrict__ S, const float* __restrict__ htab,
                      float* __restrict__ S1, float* __restrict__ S2){
    __shared__ float4 tile[1008];     // 16,128 B: swizzled [tbase,te) strip; reused as output buffer
    int bid = blockIdx.x;
    int half = bid & 1;
    int bf = bid >> 1;                // b*FB + f
    int f  = bf % FB;
    int tid = threadIdx.x;
    int tbase = half*SCH;
    int te  = tbase + SCH; if (te > TT) te = TT;
    int nst = 2*(te - tbase);
    const float4* Sg = (const float4*)S + (size_t)bf*TT*2;
    const float4* Sp = Sg + (size_t)tbase*2;
    for (int i = tid; i < nst; i += 128)
        tile[i ^ ((i>>4)&7)] = Sp[i];                    // coalesced gmem read, swizzled LDS write
    __syncthreads();
    float2 out1[CH], out2[CH];
    int t0 = tbase + tid*CH;
    bool act = (tid*CH < SCH) && (t0 < TT);
    if (act){
        const float2* hp = (const float2*)htab;
        float2 ha0 = hp[f*4+0], ha1 = hp[f*4+1], ha2 = hp[f*4+2], ha3 = hp[f*4+3];
        float2 hb0 = hp[(FB+f)*4+0], hb1 = hp[(FB+f)*4+1], hb2 = hp[(FB+f)*4+2], hb3 = hp[(FB+f)*4+3];
        float d0=0,d1=0,d2=0,d3=0;
        float2 r10={0,0}, r20={0,0}, r30={0,0}, r21={0,0}, r31={0,0}, r32={0,0};
        int ts = t0 - 15; if (ts < 0) ts = 0;
        for (int tau = ts; tau < t0; ++tau){
            float4 v0, v1;
            if (tau >= tbase){
                int i0 = 2*(tau - tbase);
                v0 = tile[i0 ^ ((i0>>4)&7)];
                v1 = tile[(i0+1) ^ ((i0>>4)&7)];
            } else {
                v0 = Sg[2*tau];
                v1 = Sg[2*tau + 1];
            }
            float2 x0 = make_float2(v0.x, v0.y), x1 = make_float2(v0.z, v0.w);
            float2 x2 = make_float2(v1.x, v1.y), x3 = make_float2(v1.z, v1.w);
            UPD(tau == 0);
        }
        for (int j = 0; j < CH; ++j){
            int t = t0 + j;
            if (t >= TT) break;
            int i0 = 2*(t - tbase);
            float4 v0 = tile[i0 ^ ((i0>>4)&7)];
            float4 v1 = tile[(i0+1) ^ ((i0>>4)&7)];
            float2 x0 = make_float2(v0.x, v0.y), x1 = make_float2(v0.z, v0.w);
            float2 x2 = make_float2(v1.x, v1.y), x3 = make_float2(v1.z, v1.w);
            UPD(t == 0);
            float trc = d0 + d1 + d2 + d3;
            float lam = trc * 0.25f;
            float e0 = d0 + lam, e1 = d1 + lam, e2 = d2 + lam, e3 = d3 + lam;
            float detP = e0*e1 - (r10.x*r10.x + r10.y*r10.y);
            float2 w00 = csub(cscale(r20, e1), cmulf(r10, r21));
            float2 w01 = csub(cscale(r30, e1), cmulf(r10, r31));
            float2 w10 = csub(cscale(r21, e0), cjmul(r10, r20));
            float2 w11 = csub(cscale(r31, e0), cjmul(r10, r30));
            float2 va = cjmul(r30, w00), vb = cjmul(r31, w10);
            float2 V10 = make_float2(va.x + vb.x, -(va.y + vb.y));
            float reV00 = r20.x*w00.x + r20.y*w00.y + r21.x*w10.x + r21.y*w10.y;
            float reV11 = r30.x*w01.x + r30.y*w01.y + r31.x*w11.x + r31.y*w11.y;
            float t00 = detP*e2 - reV00;
            float t11 = detP*e3 - reV11;
            float2 t10 = csub(cscale(r32, detP), V10);
            float detT = t00*t11 - (t10.x*t10.x + t10.y*t10.y);
            #pragma unroll
            for (int m = 0; m < 2; ++m){
                float2 h0 = m ? hb0 : ha0;
                float2 h1 = m ? hb1 : ha1;
                float2 h2 = m ? hb2 : ha2;
                float2 h3 = m ? hb3 : ha3;
                float2 g0 = csub(cscale(h0, e1), cjmul(r10, h1));
                float2 g1 = csub(cscale(h1, e0), cmulf(r10, h0));
                float2 ta = cmulf(r20, g0), tb = cmulf(r21, g1);
                float2 hh0 = make_float2(detP*h2.x - ta.x - tb.x, detP*h2.y - ta.y - tb.y);
                ta = cmulf(r30, g0); tb = cmulf(r31, g1);
                float2 hh1 = make_float2(detP*h3.x - ta.x - tb.x, detP*h3.y - ta.y - tb.y);
                float2 y20 = csub(cscale(hh0, t11), cjmul(t10, hh1));
                float2 y21 = csub(cscale(hh1, t00), cmulf(t10, hh0));
                float2 u20 = cscale(y20, detP), u21 = cscale(y21, detP);
                ta = cmulcj(y20, r20); tb = cmulcj(y21, r30);
                float2 q0 = make_float2(detT*h0.x - ta.x - tb.x, detT*h0.y - ta.y - tb.y);
                ta = cmulcj(y20, r21); tb = cmulcj(y21, r31);
                float2 q1 = make_float2(detT*h1.x - ta.x - tb.x, detT*h1.y - ta.y - tb.y);
                float2 u10 = csub(cscale(q0, e1), cjmul(r10, q1));
                float2 u11 = csub(cscale(q1, e0), cmulf(r10, q0));
                float2 den = cjmul(h0, u10), tmp;
                tmp = cjmul(h1, u11); den.x += tmp.x; den.y += tmp.y;
                tmp = cjmul(h2, u20); den.x += tmp.x; den.y += tmp.y;
                tmp = cjmul(h3, u21); den.x += tmp.x; den.y += tmp.y;
                float2 num = cjmul(u10, x0);
                tmp = cjmul(u11, x1); num.x += tmp.x; num.y += tmp.y;
                tmp = cjmul(u20, x2); num.x += tmp.x; num.y += tmp.y;
                tmp = cjmul(u21, x3); num.x += tmp.x; num.y += tmp.y;
                float2 s = cdivf(num, make_float2(den.x, -den.y));
                if (m) out2[j] = s; else out1[j] = s;
            }
        }
    }
    __syncthreads();                      // all tile reads done -> reuse as output buffers
    float2* o1 = (float2*)tile;           // [0..511]
    float2* o2 = ((float2*)tile) + 528;   // [528..1039] (ends at float4 520 <= 1008)
    if (act){
        for (int j = 0; j < CH && t0 + j < TT; ++j){
            int lt = t0 - tbase + j;
            int iw = lt ^ ((lt>>3)&7);    // bank-spread write
            o1[iw] = out1[j];
            o2[iw] = out2[j];
        }
    }
    __syncthreads();
    int nout = te - tbase;
    float2* S1g = (float2*)S1 + (size_t)bf*TT + tbase;
    float2* S2g = (float2*)S2 + (size_t)bf*TT + tbase;
    for (int i = tid; i < nout; i += 128){
        int ir = i ^ ((i>>3)&7);
        S1g[i] = o1[ir];
        S2g[i] = o2[ir];
    }
}

// ---------- pack v2 (R8-verified): coalesced LDS transpose. block = (rb, 32-t tile) ----------
__global__ __launch_bounds__(256) void k_pack(const float* __restrict__ S1, const float* __restrict__ S2,
                                              short* __restrict__ A){
    __shared__ short tile[32*708];        // 45,312 B; row = t-in-tile, col = kk (hi 0..351 | lo 352..703)
    int bid = blockIdx.x;                 // rb*32 + tb
    int tb = bid & 31, rb = bid >> 5;
    int t0 = tb*32;
    int beam = rb >> 3, b = rb & 7;
    const float2* Sp = (const float2*)(beam ? S2 : S1) + (size_t)b*FB*TT;
    int tid = threadIdx.x;
    for (int idx = tid; idx < 32*176; idx += 256){
        int bin = idx >> 5, tq = idx & 31;
        int t = t0 + tq;
        float2 s = make_float2(0.f, 0.f);
        if (bin < FB && t < TT) s = Sp[(size_t)bin*TT + t];
        int c0 = 2*bin;
        tile[tq*708 + c0]            = bf_hi(s.x);
        tile[tq*708 + c0 + 1]        = bf_hi(s.y);
        tile[tq*708 + KSEC + c0]     = bf_lo(s.x);
        tile[tq*708 + KSEC + c0 + 1] = bf_lo(s.y);
    }
    __syncthreads();
    for (int idx = tid; idx < 32*176; idx += 256){
        int tq = idx / 176, k4 = idx % 176;
        int t = t0 + tq;
        if (t < TT)
            *(short4*)&A[(size_t)(rb*TT + t)*LDK + k4*4] = *(short4*)&tile[tq*708 + k4*4];
    }
}

// ---------- irfft MFMA GEMM: frames[GM,320] = 3-segment bf16 split product ----------
__global__ __launch_bounds__(256) void k_gemm(const short* __restrict__ A, const short* __restrict__ Bt,
                                              float* __restrict__ C){
    __shared__ short As[64*40];
    __shared__ short Bs[64*40];
    int tid = threadIdx.x;
    int row0 = blockIdx.x * 64;
    int col0 = blockIdx.y * 64;
    int wave = tid >> 6, lane = tid & 63;
    int wm = wave >> 1, wn = wave & 1;
    int l15 = lane & 15, quad = lane >> 4;
    f32x4 acc00 = {0.f,0.f,0.f,0.f}, acc01 = acc00, acc10 = acc00, acc11 = acc00;
    int tr = tid >> 2;
    int tk = (tid & 3) * 8;
    int gr = row0 + tr;
    bool rok = gr < GM;
    const size_t arow = (size_t)gr*LDK;
    const size_t brow = (size_t)(col0 + tr)*LDK;
    for (int seg = 0; seg < 3; ++seg){
        int aofs = (seg == 1) ? KSEC : 0;
        int bofs = (seg == 2) ? KSEC : 0;
        for (int kt = 0; kt < KT; ++kt){
            int k0 = kt*32;
            __syncthreads();
            bf16x8 av = {};
            if (rok) av = *(const bf16x8*)&A[arow + aofs + k0 + tk];
            bf16x8 bv = *(const bf16x8*)&Bt[brow + bofs + k0 + tk];
            *(bf16x8*)&As[tr*40 + tk] = av;
            *(bf16x8*)&Bs[tr*40 + tk] = bv;
            __syncthreads();
            bf16x8 a0 = *(bf16x8*)&As[(wm*32 + l15)*40 + quad*8];
            bf16x8 a1 = *(bf16x8*)&As[(wm*32 + 16 + l15)*40 + quad*8];
            bf16x8 b0 = *(bf16x8*)&Bs[(wn*32 + l15)*40 + quad*8];
            bf16x8 b1 = *(bf16x8*)&Bs[(wn*32 + 16 + l15)*40 + quad*8];
            acc00 = __builtin_amdgcn_mfma_f32_16x16x32_bf16(a0, b0, acc00, 0, 0, 0);
            acc01 = __builtin_amdgcn_mfma_f32_16x16x32_bf16(a0, b1, acc01, 0, 0, 0);
            acc10 = __builtin_amdgcn_mfma_f32_16x16x32_bf16(a1, b0, acc10, 0, 0, 0);
            acc11 = __builtin_amdgcn_mfma_f32_16x16x32_bf16(a1, b1, acc11, 0, 0, 0);
        }
    }
    for (int r = 0; r < 4; ++r){
        int orow0 = row0 + wm*32 + quad*4 + r;
        int ocol0 = col0 + wn*32 + l15;
        if (orow0 < GM){
            C[(size_t)orow0*NFFT + ocol0]      = acc00[r];
            C[(size_t)orow0*NFFT + ocol0 + 16] = acc01[r];
        }
        if (orow0 + 16 < GM){
            C[(size_t)(orow0+16)*NFFT + ocol0]      = acc10[r];
            C[(size_t)(orow0+16)*NFFT + ocol0 + 16] = acc11[r];
        }
    }
}

// ---------- overlap-add, float4: 4 outputs/thread (wsum==2 in cropped interior) ----------
__global__ __launch_bounds__(256) void k_ola(const float* __restrict__ frames, float* __restrict__ out){
    int gid = blockIdx.x*256 + threadIdx.x;
    if (gid >= 2*BB*(LL/4)) return;
    int o4 = (gid % (LL/4))*4;
    int rb = gid / (LL/4);                 // beam*BB + b
    int i  = o4 + HOP;                     // mult of 4; r in {0,4,...,156}
    int t1 = i / HOP;
    int r  = i - t1*HOP;
    const float4* fb = (const float4*)(frames + (size_t)rb*TT*NFFT);
    float4 a = fb[(t1*NFFT + r) >> 2];
    float4 b = fb[((t1-1)*NFFT + r + HOP) >> 2];
    ((float4*)out)[gid] = make_float4(0.5f*(a.x+b.x), 0.5f*(a.y+b.y), 0.5f*(a.z+b.z), 0.5f*(a.w+b.w));
}

extern "C" void kernel_launch(void* const* d_in, const int* in_sizes, int n_in,
                              void* d_out, int out_size, void* d_ws, size_t ws_size,
                              hipStream_t stream){
    const float* in  = (const float*)d_in[0];   // [B, L, C] fp32
    const float* win = (const float*)d_in[1];   // [320] fp32
    float* ws = (float*)d_ws;
    // ws (floats): mean 32 | invmax 8 | htab 2576 | pad -> header 3072
    //              | S1 (2,578,576) | S2 (2,578,576) | S (10,314,304)   total ~62 MB
    // aliases: part -> S1 head (dead before k_anorm); Ahi/Alo -> S1+S2 (dead after k_gstft);
    //          Bts + Bt -> head of d_out (dead until k_ola fully overwrites; NOT in S — R13 bug);
    //          A_ir -> S (post-scan); frames -> S1/S2 (post-pack)
    float* mean   = ws;
    float* invmax = ws + 32;
    float* htab   = ws + 48;
    float* S1     = ws + 3072;
    size_t nS1 = (size_t)2*BB*FB*TT;            // 2,578,576 floats
    float* S2 = S1 + nS1;
    float* S  = S2 + nS1;                       // 10,314,304 floats
    float* part = S1;
    short* Ahi = (short*)S1;                    // 8*4*160320 = 5,130,240 shorts
    short* Alo = Ahi + (size_t)BB*CC*NPAD;      // total 10,260,480 shorts <= S1+S2 (10,314,304 short-equiv)
    short* Bts = (short*)d_out;                 // 245,760 shorts (= 122,880 floats)
    short* Bt  = (short*)((float*)d_out + 131072); // 225,280 shorts at float-offset 131072 (16B aligned)
    short* A  = (short*)S;                      // irfft A: 16016*704 bf16
    float* frames = S1;                         // 16016*320 floats over dead S1+S2

    int ngen = 2*FB*CC + 384*640 + NFFT*LDK;    // fused table generation
    k_gen<<<dim3((ngen + 255)/256), dim3(256), 0, stream>>>(win, htab, Bts, Bt);
    k_stats1<<<dim3(BB*RBLK), dim3(256), 0, stream>>>(in, part);
    k_stats2<<<dim3(BB), dim3(128), 0, stream>>>(part, mean, invmax);
    k_anorm<<<dim3((BB*CC*(NPAD/8) + 255)/256), dim3(256), 0, stream>>>(in, mean, invmax, Ahi, Alo);
    k_gstft<<<dim3(BB*TP*CC/64, 6), dim3(256), 0, stream>>>(Ahi, Alo, Bts, S);
    k_scan<<<dim3(2*BB*FB), dim3(128), 0, stream>>>(S, htab, S1, S2);
    k_pack<<<dim3(512), dim3(256), 0, stream>>>(S1, S2, A);
    k_gemm<<<dim3((GM + 63)/64, NFFT/64), dim3(256), 0, stream>>>(A, Bt, frames);
    k_ola<<<dim3((2*BB*(LL/4) + 255)/256), dim3(256), 0, stream>>>(frames, (float*)d_out);
}

// Round 16
// 224.286 us; speedup vs baseline: 1.0963x; 1.0554x over previous
//
#include <hip/hip_runtime.h>
#include <hip/hip_bf16.h>
#include <math.h>

#define BB 8
#define LL 160000
#define CC 4
#define NFFT 320
#define HOP 160
#define FB 161          // rfft bins
#define TT 1001         // frames
#define TP 1024         // padded frames per batch (t-slots) for STFT GEMM
#define RBLK 128        // stats blocks per batch
#define PI_D 3.14159265358979323846
#define NPAD 160320     // reflect-padded samples per (b,c): p in [-160, 160159]

#define CH 2            // scan t-chunk per thread (CH=2 + 256-thread blocks)
#define SCH 504         // scan outputs per half-block (2 halves cover 1001)
#define KWARM 7         // warm-up frames; 0.05^7 ~ 8e-10 rel << bf16 error floor (4.9e-4)

#define GM 16016        // irfft GEMM M = 2*BB*TT rows (beam,b,t)
#define KSEC 352        // irfft padded K per split-section (322 used)
#define LDK 704         // irfft A/Bt leading dim = 2 sections
#define KT 11           // irfft K-tiles of 32 per section
// NOTE: LDS row stride for bf16x8 tiles MUST keep rows 16B-aligned.
// stride 40 shorts = 80 B (aligned, ~2-way conflicts, cheap — R5: 61 us).
// stride 36 shorts = 72 B (misaligned b128 -> 3x slowdown — R9: 177 us). Do not repeat.
// LIFETIME NOTE (R13 bug): Bt/Bts must NOT live in the S region — k_gstft overwrites
// ALL of S. Both live in d_out's head (dead until k_ola fully overwrites at the end).

typedef __attribute__((ext_vector_type(8))) short bf16x8;
typedef __attribute__((ext_vector_type(4))) float f32x4;

__device__ __forceinline__ float2 cmulf(float2 a, float2 b){           // a*b
    return make_float2(a.x*b.x - a.y*b.y, a.x*b.y + a.y*b.x);
}
__device__ __forceinline__ float2 cmulcj(float2 a, float2 b){          // a*conj(b)
    return make_float2(a.x*b.x + a.y*b.y, a.y*b.x - a.x*b.y);
}
__device__ __forceinline__ float2 cjmul(float2 a, float2 b){           // conj(a)*b
    return make_float2(a.x*b.x + a.y*b.y, a.x*b.y - a.y*b.x);
}
__device__ __forceinline__ float2 csub(float2 a, float2 b){ return make_float2(a.x-b.x, a.y-b.y); }
__device__ __forceinline__ float2 cscale(float2 a, float s){ return make_float2(a.x*s, a.y*s); }
__device__ __forceinline__ float2 cdivf(float2 a, float2 b){           // a/b
    float inv = 1.0f/(b.x*b.x + b.y*b.y);
    return make_float2((a.x*b.x + a.y*b.y)*inv, (a.y*b.x - a.x*b.y)*inv);
}
__device__ __forceinline__ short bf_hi(float v){
    __hip_bfloat16 h = __float2bfloat16(v);
    short s; __builtin_memcpy(&s, &h, 2); return s;
}
__device__ __forceinline__ short bf_lo(float v){
    __hip_bfloat16 h = __float2bfloat16(v);
    float r = v - __bfloat162float(h);
    __hip_bfloat16 l = __float2bfloat16(r);
    short s; __builtin_memcpy(&s, &l, 2); return s;
}

// ---------- fused table generator: htab | Bts (STFT B) | Bt (irfft B) ----------
__global__ void k_gen(const float* __restrict__ win, float* __restrict__ htab,
                      short* __restrict__ Bts, short* __restrict__ Bt){
    int gid = blockIdx.x*256 + threadIdx.x;
    if (gid < 2*FB*CC){
        int i = gid;
        int c = i & 3;
        int k = (i >> 2) % FB;
        int m = i / (FB*CC);
        double coef = 2.0*PI_D*50.0*0.027*sin(40.0*PI_D/180.0)/340.0;
        double sgn = (m == 0) ? -1.0 : 1.0;
        double ph = sgn*coef*(double)k*(double)c;
        double s, c2;
        sincos(ph, &s, &c2);
        ((float2*)htab)[i] = make_float2((float)c2, (float)s);
        return;
    }
    gid -= 2*FB*CC;
    if (gid < 384*640){
        int col = gid / 640, kk = gid % 640;
        int n = (kk >= 320) ? kk - 320 : kk;
        int sec = (kk >= 320) ? 1 : 0;
        float v = 0.f;
        if (col < 2*FB){
            int k = col >> 1;
            double th = 2.0*PI_D*(double)k*(double)n/320.0;
            double s, co; sincos(th, &s, &co);
            double tw = (col & 1) ? -s : co;
            v = (float)((double)win[n]*tw);
        }
        Bts[gid] = sec ? bf_lo(v) : bf_hi(v);
        return;
    }
    gid -= 384*640;
    if (gid < NFFT*LDK){
        int n = gid / LDK, kk = gid % LDK;
        int sec = (kk >= KSEC) ? 1 : 0;
        int kk2 = kk - (sec ? KSEC : 0);
        float v = 0.f;
        if (kk2 < 2*FB){
            int bin = kk2 >> 1;
            double c = ((bin == 0 || bin == 160) ? 1.0 : 2.0) / 320.0;
            double th = 2.0*PI_D*(double)bin*(double)n/320.0;
            double s, co; sincos(th, &s, &co);
            v = (float)((kk2 & 1) ? -c*s : c*co);
        }
        Bt[(size_t)n*LDK + kk] = sec ? bf_lo(v) : bf_hi(v);
    }
}

// ---------- stage 1: per-(b,chunk) partial {sum4, min4, max4} ----------
__global__ __launch_bounds__(256) void k_stats1(const float* __restrict__ in, float* __restrict__ part){
    __shared__ float4 s4[256];
    __shared__ float4 mn4[256];
    __shared__ float4 mx4[256];
    int b = blockIdx.x / RBLK, chunk = blockIdx.x % RBLK;
    int tid = threadIdx.x;
    const float4* p = (const float4*)(in + (size_t)b*LL*CC);
    const int per = LL / RBLK;
    int start = chunk*per;
    float4 s  = make_float4(0.f,0.f,0.f,0.f);
    float4 mn = make_float4( 3.4e38f, 3.4e38f, 3.4e38f, 3.4e38f);
    float4 mx = make_float4(-3.4e38f,-3.4e38f,-3.4e38f,-3.4e38f);
    for (int i = start + tid; i < start + per; i += 256){
        float4 v = p[i];
        s.x += v.x; s.y += v.y; s.z += v.z; s.w += v.w;
        mn.x = fminf(mn.x, v.x); mn.y = fminf(mn.y, v.y); mn.z = fminf(mn.z, v.z); mn.w = fminf(mn.w, v.w);
        mx.x = fmaxf(mx.x, v.x); mx.y = fmaxf(mx.y, v.y); mx.z = fmaxf(mx.z, v.z); mx.w = fmaxf(mx.w, v.w);
    }
    s4[tid] = s; mn4[tid] = mn; mx4[tid] = mx;
    __syncthreads();
    for (int st = 128; st >= 1; st >>= 1){
        if (tid < st){
            float4 a = s4[tid], c = s4[tid+st];
            s4[tid] = make_float4(a.x+c.x, a.y+c.y, a.z+c.z, a.w+c.w);
            float4 d = mn4[tid], e = mn4[tid+st];
            mn4[tid] = make_float4(fminf(d.x,e.x), fminf(d.y,e.y), fminf(d.z,e.z), fminf(d.w,e.w));
            float4 f = mx4[tid], g = mx4[tid+st];
            mx4[tid] = make_float4(fmaxf(f.x,g.x), fmaxf(f.y,g.y), fmaxf(f.z,g.z), fmaxf(f.w,g.w));
        }
        __syncthreads();
    }
    if (tid == 0){
        float* dst = part + (size_t)(b*RBLK + chunk)*12;
        float4 a = s4[0], d = mn4[0], f = mx4[0];
        dst[0]=a.x; dst[1]=a.y; dst[2]=a.z; dst[3]=a.w;
        dst[4]=d.x; dst[5]=d.y; dst[6]=d.z; dst[7]=d.w;
        dst[8]=f.x; dst[9]=f.y; dst[10]=f.z; dst[11]=f.w;
    }
}

// ---------- stage 2: finalize mean + invmax per batch ----------
__global__ __launch_bounds__(128) void k_stats2(const float* __restrict__ part,
                                                float* __restrict__ mean, float* __restrict__ invmax){
    __shared__ float4 s4[128];
    __shared__ float4 mn4[128];
    __shared__ float4 mx4[128];
    int b = blockIdx.x, tid = threadIdx.x;
    const float* src = part + (size_t)(b*RBLK + tid)*12;
    s4[tid]  = make_float4(src[0], src[1], src[2], src[3]);
    mn4[tid] = make_float4(src[4], src[5], src[6], src[7]);
    mx4[tid] = make_float4(src[8], src[9], src[10], src[11]);
    __syncthreads();
    for (int st = 64; st >= 1; st >>= 1){
        if (tid < st){
            float4 a = s4[tid], c = s4[tid+st];
            s4[tid] = make_float4(a.x+c.x, a.y+c.y, a.z+c.z, a.w+c.w);
            float4 d = mn4[tid], e = mn4[tid+st];
            mn4[tid] = make_float4(fminf(d.x,e.x), fminf(d.y,e.y), fminf(d.z,e.z), fminf(d.w,e.w));
            float4 f = mx4[tid], g = mx4[tid+st];
            mx4[tid] = make_float4(fmaxf(f.x,g.x), fmaxf(f.y,g.y), fmaxf(f.z,g.z), fmaxf(f.w,g.w));
        }
        __syncthreads();
    }
    if (tid == 0){
        float4 sum = s4[0], mn = mn4[0], mx = mx4[0];
        float m0 = sum.x*(1.0f/LL), m1 = sum.y*(1.0f/LL), m2 = sum.z*(1.0f/LL), m3 = sum.w*(1.0f/LL);
        mean[b*4+0]=m0; mean[b*4+1]=m1; mean[b*4+2]=m2; mean[b*4+3]=m3;
        float a0 = fmaxf(mx.x - m0, m0 - mn.x);
        float a1 = fmaxf(mx.y - m1, m1 - mn.y);
        float a2 = fmaxf(mx.z - m2, m2 - mn.z);
        float a3 = fmaxf(mx.w - m3, m3 - mn.w);
        invmax[b] = 1.0f / fmaxf(fmaxf(a0, a1), fmaxf(a2, a3));
    }
}

// ---------- A-normalize: reflect-padded normalized bf16 hi/lo planes Ahi/Alo[b][c][NPAD] ----------
__global__ __launch_bounds__(256) void k_anorm(const float* __restrict__ in,
        const float* __restrict__ mean, const float* __restrict__ invmax,
        short* __restrict__ Ahi, short* __restrict__ Alo){
    int gid = blockIdx.x*256 + threadIdx.x;
    if (gid >= BB*CC*(NPAD/8)) return;
    int p8 = gid % (NPAD/8);
    int bc = gid / (NPAD/8);
    int b = bc >> 2;
    float mc = mean[bc];
    float iv = invmax[b];
    const float* px = in + (size_t)b*LL*CC + (bc & 3);
    bf16x8 h8, l8;
    #pragma unroll
    for (int j = 0; j < 8; ++j){
        int p = p8*8 + j - 160;
        int m2 = p < 0 ? -p : (p >= LL ? 2*LL - 2 - p : p);
        float v = (px[(size_t)m2*CC] - mc) * iv;
        __hip_bfloat16 h = __float2bfloat16(v);
        float r = v - __bfloat162float(h);
        __hip_bfloat16 l = __float2bfloat16(r);
        short hs, ls; __builtin_memcpy(&hs, &h, 2); __builtin_memcpy(&ls, &l, 2);
        h8[j] = hs; l8[j] = ls;
    }
    size_t o = (size_t)bc*NPAD + (size_t)p8*8;
    *(bf16x8*)&Ahi[o] = h8;
    *(bf16x8*)&Alo[o] = l8;
}

// ---------- STFT as MFMA GEMM (R5 structure, precomputed A planes): rows=(b,t,c), cols=(k,ri) ----------
// S out layout: complex S[b][k][t][c], c fastest (two float4 per (b,k,t))
__global__ __launch_bounds__(256) void k_gstft(const short* __restrict__ Ahi, const short* __restrict__ Alo,
        const short* __restrict__ Bts, float* __restrict__ S){
    __shared__ short stage[4*2560];          // Ah|Al|Bh|Bl, rows stride 40 shorts (80B, 16B-aligned)
    short* Ah = stage;
    short* Al = stage + 2560;
    short* Bh = stage + 5120;
    short* Bl = stage + 7680;
    float* Ct = (float*)stage;               // 64 x 66 floats (16.9 KB) overlays after K-loop
    int tid = threadIdx.x;
    int row0 = blockIdx.x*64;                // over b*TP*CC rows
    int col0 = blockIdx.y*64;
    int b  = row0 >> 12;                     // TP*CC = 4096 rows per batch
    int t0 = (row0 & 4095) >> 2;
    int tr = tid >> 2, tq = tid & 3, tk = tq*8;
    int tloc = t0 + (tr >> 2);
    int c    = tr & 3;
    bool vt  = tloc < TT;
    const short* pah = Ahi + (size_t)(b*4 + c)*NPAD;
    const short* pal = Alo + (size_t)(b*4 + c)*NPAD;
    int npbase = tloc*160;                   // p = tloc*HOP - HOP + n  ->  np = p + 160 = tloc*160 + n
    int wave = tid >> 6, lane = tid & 63;
    int wm = wave >> 1, wn = wave & 1;
    int l15 = lane & 15, quad = lane >> 4;
    f32x4 acc00 = {0.f,0.f,0.f,0.f}, acc01 = acc00, acc10 = acc00, acc11 = acc00;
    for (int kt = 0; kt < 10; ++kt){
        int k0 = kt*32;
        __syncthreads();
        bf16x8 hv = {}, lv = {};
        if (vt){
            hv = *(const bf16x8*)&pah[npbase + k0 + tk];
            lv = *(const bf16x8*)&pal[npbase + k0 + tk];
        }
        *(bf16x8*)&Ah[tr*40 + tk] = hv;
        *(bf16x8*)&Al[tr*40 + tk] = lv;
        const short* bp = Bts + (size_t)(col0 + tr)*640 + k0 + tk;
        *(bf16x8*)&Bh[tr*40 + tk] = *(const bf16x8*)bp;
        *(bf16x8*)&Bl[tr*40 + tk] = *(const bf16x8*)(bp + 320);
        __syncthreads();
        bf16x8 a0h = *(bf16x8*)&Ah[(wm*32 + l15)*40 + quad*8];
        bf16x8 a1h = *(bf16x8*)&Ah[(wm*32 + 16 + l15)*40 + quad*8];
        bf16x8 a0l = *(bf16x8*)&Al[(wm*32 + l15)*40 + quad*8];
        bf16x8 a1l = *(bf16x8*)&Al[(wm*32 + 16 + l15)*40 + quad*8];
        bf16x8 b0h = *(bf16x8*)&Bh[(wn*32 + l15)*40 + quad*8];
        bf16x8 b1h = *(bf16x8*)&Bh[(wn*32 + 16 + l15)*40 + quad*8];
        bf16x8 b0l = *(bf16x8*)&Bl[(wn*32 + l15)*40 + quad*8];
        bf16x8 b1l = *(bf16x8*)&Bl[(wn*32 + 16 + l15)*40 + quad*8];
        acc00 = __builtin_amdgcn_mfma_f32_16x16x32_bf16(a0h, b0h, acc00, 0, 0, 0);
        acc01 = __builtin_amdgcn_mfma_f32_16x16x32_bf16(a0h, b1h, acc01, 0, 0, 0);
        acc10 = __builtin_amdgcn_mfma_f32_16x16x32_bf16(a1h, b0h, acc10, 0, 0, 0);
        acc11 = __builtin_amdgcn_mfma_f32_16x16x32_bf16(a1h, b1h, acc11, 0, 0, 0);
        acc00 = __builtin_amdgcn_mfma_f32_16x16x32_bf16(a0l, b0h, acc00, 0, 0, 0);
        acc01 = __builtin_amdgcn_mfma_f32_16x16x32_bf16(a0l, b1h, acc01, 0, 0, 0);
        acc10 = __builtin_amdgcn_mfma_f32_16x16x32_bf16(a1l, b0h, acc10, 0, 0, 0);
        acc11 = __builtin_amdgcn_mfma_f32_16x16x32_bf16(a1l, b1h, acc11, 0, 0, 0);
        acc00 = __builtin_amdgcn_mfma_f32_16x16x32_bf16(a0h, b0l, acc00, 0, 0, 0);
        acc01 = __builtin_amdgcn_mfma_f32_16x16x32_bf16(a0h, b1l, acc01, 0, 0, 0);
        acc10 = __builtin_amdgcn_mfma_f32_16x16x32_bf16(a1h, b0l, acc10, 0, 0, 0);
        acc11 = __builtin_amdgcn_mfma_f32_16x16x32_bf16(a1h, b1l, acc11, 0, 0, 0);
    }
    // epilogue: LDS transpose, out in S layout
    __syncthreads();                       // staging reads done; Ct overlays
    #pragma unroll
    for (int r = 0; r < 4; ++r){
        int rl = wm*32 + quad*4 + r;       // channel = r (rl & 3 == r)
        Ct[rl*66 + wn*32 + l15]           = acc00[r];
        Ct[rl*66 + wn*32 + l15 + 16]      = acc01[r];
        Ct[(rl+16)*66 + wn*32 + l15]      = acc10[r];
        Ct[(rl+16)*66 + wn*32 + l15 + 16] = acc11[r];
    }
    __syncthreads();
    int tl = tid & 15, h = (tid >> 4) & 1, kq = tid >> 5;
    int t = t0 + tl;
    if (t < TT){
        float4* S4 = (float4*)S;
        for (int kk = kq; kk < 32; kk += 8){
            int kg = (col0 >> 1) + kk;
            if (kg < FB){
                float2 e0 = *(float2*)&Ct[(tl*4 + 2*h)*66 + 2*kk];
                float2 e1 = *(float2*)&Ct[(tl*4 + 2*h + 1)*66 + 2*kk];
                S4[((size_t)(b*FB + kg)*TT + t)*2 + h] = make_float4(e0.x, e0.y, e1.x, e1.y);
            }
        }
    }
}

// covariance recurrence update: R = a*R + wg*outer(X), a/wg handle first-frame
#define UPD(first) do{ \
    float aa = (first) ? 0.f : 0.05f; float wg = (first) ? 1.f : 0.95f; \
    float y0x=wg*x0.x, y0y=wg*x0.y, y1x=wg*x1.x, y1y=wg*x1.y; \
    float y2x=wg*x2.x, y2y=wg*x2.y, y3x=wg*x3.x, y3y=wg*x3.y; \
    d0 = aa*d0 + y0x*x0.x + y0y*x0.y; \
    d1 = aa*d1 + y1x*x1.x + y1y*x1.y; \
    d2 = aa*d2 + y2x*x2.x + y2y*x2.y; \
    d3 = aa*d3 + y3x*x3.x + y3y*x3.y; \
    r10.x = aa*r10.x + y1x*x0.x + y1y*x0.y;  r10.y = aa*r10.y + y1y*x0.x - y1x*x0.y; \
    r20.x = aa*r20.x + y2x*x0.x + y2y*x0.y;  r20.y = aa*r20.y + y2y*x0.x - y2x*x0.y; \
    r30.x = aa*r30.x + y3x*x0.x + y3y*x0.y;  r30.y = aa*r30.y + y3y*x0.x - y3x*x0.y; \
    r21.x = aa*r21.x + y2x*x1.x + y2y*x1.y;  r21.y = aa*r21.y + y2y*x1.x - y2x*x1.y; \
    r31.x = aa*r31.x + y3x*x1.x + y3y*x1.y;  r31.y = aa*r31.y + y3y*x1.x - y3x*x1.y; \
    r32.x = aa*r32.x + y3x*x2.x + y3y*x2.y;  r32.y = aa*r32.y + y3y*x2.x - y3x*x2.y; \
}while(0)

// ---------- LDS-staged chunked scan, half-strip, CH=2 x 256 threads, 7-frame warm-up ----------
// Warm-up frames below tbase (threads 0..3) come straight from gmem.
// Division/sqrt-free Schur-adjugate solve (scale-invariance of s). S1/S2 layout: complex [b][f][t]
__global__ __launch_bounds__(256) void k_scan(const float* __restrict__ S, const float* __restrict__ htab,
                      float* __restrict__ S1, float* __restrict__ S2){
    __shared__ float4 tile[1008];     // 16,128 B: swizzled [tbase,te) strip; reused as output buffer
    int bid = blockIdx.x;
    int half = bid & 1;
    int bf = bid >> 1;                // b*FB + f
    int f  = bf % FB;
    int tid = threadIdx.x;
    int tbase = half*SCH;
    int te  = tbase + SCH; if (te > TT) te = TT;
    int nst = 2*(te - tbase);
    const float4* Sg = (const float4*)S + (size_t)bf*TT*2;
    const float4* Sp = Sg + (size_t)tbase*2;
    for (int i = tid; i < nst; i += 256)
        tile[i ^ ((i>>4)&7)] = Sp[i];                    // coalesced gmem read, swizzled LDS write
    __syncthreads();
    float2 out1[CH], out2[CH];
    int t0 = tbase + tid*CH;
    bool act = (tid*CH < SCH) && (t0 < TT);
    if (act){
        const float2* hp = (const float2*)htab;
        float2 ha0 = hp[f*4+0], ha1 = hp[f*4+1], ha2 = hp[f*4+2], ha3 = hp[f*4+3];
        float2 hb0 = hp[(FB+f)*4+0], hb1 = hp[(FB+f)*4+1], hb2 = hp[(FB+f)*4+2], hb3 = hp[(FB+f)*4+3];
        float d0=0,d1=0,d2=0,d3=0;
        float2 r10={0,0}, r20={0,0}, r30={0,0}, r21={0,0}, r31={0,0}, r32={0,0};
        int ts = t0 - KWARM; if (ts < 0) ts = 0;
        for (int tau = ts; tau < t0; ++tau){
            float4 v0, v1;
            if (tau >= tbase){
                int i0 = 2*(tau - tbase);
                v0 = tile[i0 ^ ((i0>>4)&7)];
                v1 = tile[(i0+1) ^ ((i0>>4)&7)];
            } else {
                v0 = Sg[2*tau];
                v1 = Sg[2*tau + 1];
            }
            float2 x0 = make_float2(v0.x, v0.y), x1 = make_float2(v0.z, v0.w);
            float2 x2 = make_float2(v1.x, v1.y), x3 = make_float2(v1.z, v1.w);
            UPD(tau == 0);
        }
        for (int j = 0; j < CH; ++j){
            int t = t0 + j;
            if (t >= TT) break;
            int i0 = 2*(t - tbase);
            float4 v0 = tile[i0 ^ ((i0>>4)&7)];
            float4 v1 = tile[(i0+1) ^ ((i0>>4)&7)];
            float2 x0 = make_float2(v0.x, v0.y), x1 = make_float2(v0.z, v0.w);
            float2 x2 = make_float2(v1.x, v1.y), x3 = make_float2(v1.z, v1.w);
            UPD(t == 0);
            float trc = d0 + d1 + d2 + d3;
            float lam = trc * 0.25f;
            float e0 = d0 + lam, e1 = d1 + lam, e2 = d2 + lam, e3 = d3 + lam;
            float detP = e0*e1 - (r10.x*r10.x + r10.y*r10.y);
            float2 w00 = csub(cscale(r20, e1), cmulf(r10, r21));
            float2 w01 = csub(cscale(r30, e1), cmulf(r10, r31));
            float2 w10 = csub(cscale(r21, e0), cjmul(r10, r20));
            float2 w11 = csub(cscale(r31, e0), cjmul(r10, r30));
            float2 va = cjmul(r30, w00), vb = cjmul(r31, w10);
            float2 V10 = make_float2(va.x + vb.x, -(va.y + vb.y));
            float reV00 = r20.x*w00.x + r20.y*w00.y + r21.x*w10.x + r21.y*w10.y;
            float reV11 = r30.x*w01.x + r30.y*w01.y + r31.x*w11.x + r31.y*w11.y;
            float t00 = detP*e2 - reV00;
            float t11 = detP*e3 - reV11;
            float2 t10 = csub(cscale(r32, detP), V10);
            float detT = t00*t11 - (t10.x*t10.x + t10.y*t10.y);
            #pragma unroll
            for (int m = 0; m < 2; ++m){
                float2 h0 = m ? hb0 : ha0;
                float2 h1 = m ? hb1 : ha1;
                float2 h2 = m ? hb2 : ha2;
                float2 h3 = m ? hb3 : ha3;
                float2 g0 = csub(cscale(h0, e1), cjmul(r10, h1));
                float2 g1 = csub(cscale(h1, e0), cmulf(r10, h0));
                float2 ta = cmulf(r20, g0), tb = cmulf(r21, g1);
                float2 hh0 = make_float2(detP*h2.x - ta.x - tb.x, detP*h2.y - ta.y - tb.y);
                ta = cmulf(r30, g0); tb = cmulf(r31, g1);
                float2 hh1 = make_float2(detP*h3.x - ta.x - tb.x, detP*h3.y - ta.y - tb.y);
                float2 y20 = csub(cscale(hh0, t11), cjmul(t10, hh1));
                float2 y21 = csub(cscale(hh1, t00), cmulf(t10, hh0));
                float2 u20 = cscale(y20, detP), u21 = cscale(y21, detP);
                ta = cmulcj(y20, r20); tb = cmulcj(y21, r30);
                float2 q0 = make_float2(detT*h0.x - ta.x - tb.x, detT*h0.y - ta.y - tb.y);
                ta = cmulcj(y20, r21); tb = cmulcj(y21, r31);
                float2 q1 = make_float2(detT*h1.x - ta.x - tb.x, detT*h1.y - ta.y - tb.y);
                float2 u10 = csub(cscale(q0, e1), cjmul(r10, q1));
                float2 u11 = csub(cscale(q1, e0), cmulf(r10, q0));
                float2 den = cjmul(h0, u10), tmp;
                tmp = cjmul(h1, u11); den.x += tmp.x; den.y += tmp.y;
                tmp = cjmul(h2, u20); den.x += tmp.x; den.y += tmp.y;
                tmp = cjmul(h3, u21); den.x += tmp.x; den.y += tmp.y;
                float2 num = cjmul(u10, x0);
                tmp = cjmul(u11, x1); num.x += tmp.x; num.y += tmp.y;
                tmp = cjmul(u20, x2); num.x += tmp.x; num.y += tmp.y;
                tmp = cjmul(u21, x3); num.x += tmp.x; num.y += tmp.y;
                float2 s = cdivf(num, make_float2(den.x, -den.y));
                if (m) out2[j] = s; else out1[j] = s;
            }
        }
    }
    __syncthreads();                      // all tile reads done -> reuse as output buffers
    float2* o1 = (float2*)tile;           // [0..511]
    float2* o2 = ((float2*)tile) + 528;   // [528..1039] (ends at float4 520 <= 1008)
    if (act){
        for (int j = 0; j < CH && t0 + j < TT; ++j){
            int lt = t0 - tbase + j;
            int iw = lt ^ ((lt>>3)&7);    // bank-spread write
            o1[iw] = out1[j];
            o2[iw] = out2[j];
        }
    }
    __syncthreads();
    int nout = te - tbase;
    float2* S1g = (float2*)S1 + (size_t)bf*TT + tbase;
    float2* S2g = (float2*)S2 + (size_t)bf*TT + tbase;
    for (int i = tid; i < nout; i += 256){
        int ir = i ^ ((i>>3)&7);
        S1g[i] = o1[ir];
        S2g[i] = o2[ir];
    }
}

// ---------- pack v2 (R8-verified): coalesced LDS transpose. block = (rb, 32-t tile) ----------
__global__ __launch_bounds__(256) void k_pack(const float* __restrict__ S1, const float* __restrict__ S2,
                                              short* __restrict__ A){
    __shared__ short tile[32*708];        // 45,312 B; row = t-in-tile, col = kk (hi 0..351 | lo 352..703)
    int bid = blockIdx.x;                 // rb*32 + tb
    int tb = bid & 31, rb = bid >> 5;
    int t0 = tb*32;
    int beam = rb >> 3, b = rb & 7;
    const float2* Sp = (const float2*)(beam ? S2 : S1) + (size_t)b*FB*TT;
    int tid = threadIdx.x;
    for (int idx = tid; idx < 32*176; idx += 256){
        int bin = idx >> 5, tq = idx & 31;
        int t = t0 + tq;
        float2 s = make_float2(0.f, 0.f);
        if (bin < FB && t < TT) s = Sp[(size_t)bin*TT + t];
        int c0 = 2*bin;
        tile[tq*708 + c0]            = bf_hi(s.x);
        tile[tq*708 + c0 + 1]        = bf_hi(s.y);
        tile[tq*708 + KSEC + c0]     = bf_lo(s.x);
        tile[tq*708 + KSEC + c0 + 1] = bf_lo(s.y);
    }
    __syncthreads();
    for (int idx = tid; idx < 32*176; idx += 256){
        int tq = idx / 176, k4 = idx % 176;
        int t = t0 + tq;
        if (t < TT)
            *(short4*)&A[(size_t)(rb*TT + t)*LDK + k4*4] = *(short4*)&tile[tq*708 + k4*4];
    }
}

// ---------- irfft MFMA GEMM: frames[GM,320] = 3-segment bf16 split product ----------
__global__ __launch_bounds__(256) void k_gemm(const short* __restrict__ A, const short* __restrict__ Bt,
                                              float* __restrict__ C){
    __shared__ short As[64*40];
    __shared__ short Bs[64*40];
    int tid = threadIdx.x;
    int row0 = blockIdx.x * 64;
    int col0 = blockIdx.y * 64;
    int wave = tid >> 6, lane = tid & 63;
    int wm = wave >> 1, wn = wave & 1;
    int l15 = lane & 15, quad = lane >> 4;
    f32x4 acc00 = {0.f,0.f,0.f,0.f}, acc01 = acc00, acc10 = acc00, acc11 = acc00;
    int tr = tid >> 2;
    int tk = (tid & 3) * 8;
    int gr = row0 + tr;
    bool rok = gr < GM;
    const size_t arow = (size_t)gr*LDK;
    const size_t brow = (size_t)(col0 + tr)*LDK;
    for (int seg = 0; seg < 3; ++seg){
        int aofs = (seg == 1) ? KSEC : 0;
        int bofs = (seg == 2) ? KSEC : 0;
        for (int kt = 0; kt < KT; ++kt){
            int k0 = kt*32;
            __syncthreads();
            bf16x8 av = {};
            if (rok) av = *(const bf16x8*)&A[arow + aofs + k0 + tk];
            bf16x8 bv = *(const bf16x8*)&Bt[brow + bofs + k0 + tk];
            *(bf16x8*)&As[tr*40 + tk] = av;
            *(bf16x8*)&Bs[tr*40 + tk] = bv;
            __syncthreads();
            bf16x8 a0 = *(bf16x8*)&As[(wm*32 + l15)*40 + quad*8];
            bf16x8 a1 = *(bf16x8*)&As[(wm*32 + 16 + l15)*40 + quad*8];
            bf16x8 b0 = *(bf16x8*)&Bs[(wn*32 + l15)*40 + quad*8];
            bf16x8 b1 = *(bf16x8*)&Bs[(wn*32 + 16 + l15)*40 + quad*8];
            acc00 = __builtin_amdgcn_mfma_f32_16x16x32_bf16(a0, b0, acc00, 0, 0, 0);
            acc01 = __builtin_amdgcn_mfma_f32_16x16x32_bf16(a0, b1, acc01, 0, 0, 0);
            acc10 = __builtin_amdgcn_mfma_f32_16x16x32_bf16(a1, b0, acc10, 0, 0, 0);
            acc11 = __builtin_amdgcn_mfma_f32_16x16x32_bf16(a1, b1, acc11, 0, 0, 0);
        }
    }
    for (int r = 0; r < 4; ++r){
        int orow0 = row0 + wm*32 + quad*4 + r;
        int ocol0 = col0 + wn*32 + l15;
        if (orow0 < GM){
            C[(size_t)orow0*NFFT + ocol0]      = acc00[r];
            C[(size_t)orow0*NFFT + ocol0 + 16] = acc01[r];
        }
        if (orow0 + 16 < GM){
            C[(size_t)(orow0+16)*NFFT + ocol0]      = acc10[r];
            C[(size_t)(orow0+16)*NFFT + ocol0 + 16] = acc11[r];
        }
    }
}

// ---------- overlap-add, float4: 4 outputs/thread (wsum==2 in cropped interior) ----------
__global__ __launch_bounds__(256) void k_ola(const float* __restrict__ frames, float* __restrict__ out){
    int gid = blockIdx.x*256 + threadIdx.x;
    if (gid >= 2*BB*(LL/4)) return;
    int o4 = (gid % (LL/4))*4;
    int rb = gid / (LL/4);                 // beam*BB + b
    int i  = o4 + HOP;                     // mult of 4; r in {0,4,...,156}
    int t1 = i / HOP;
    int r  = i - t1*HOP;
    const float4* fb = (const float4*)(frames + (size_t)rb*TT*NFFT);
    float4 a = fb[(t1*NFFT + r) >> 2];
    float4 b = fb[((t1-1)*NFFT + r + HOP) >> 2];
    ((float4*)out)[gid] = make_float4(0.5f*(a.x+b.x), 0.5f*(a.y+b.y), 0.5f*(a.z+b.z), 0.5f*(a.w+b.w));
}

extern "C" void kernel_launch(void* const* d_in, const int* in_sizes, int n_in,
                              void* d_out, int out_size, void* d_ws, size_t ws_size,
                              hipStream_t stream){
    const float* in  = (const float*)d_in[0];   // [B, L, C] fp32
    const float* win = (const float*)d_in[1];   // [320] fp32
    float* ws = (float*)d_ws;
    // ws (floats): mean 32 | invmax 8 | htab 2576 | pad -> header 3072
    //              | S1 (2,578,576) | S2 (2,578,576) | S (10,314,304)   total ~62 MB
    // aliases: part -> S1 head (dead before k_anorm); Ahi/Alo -> S1+S2 (dead after k_gstft);
    //          Bts + Bt -> head of d_out (dead until k_ola fully overwrites; NOT in S — R13 bug);
    //          A_ir -> S (post-scan); frames -> S1/S2 (post-pack)
    float* mean   = ws;
    float* invmax = ws + 32;
    float* htab   = ws + 48;
    float* S1     = ws + 3072;
    size_t nS1 = (size_t)2*BB*FB*TT;            // 2,578,576 floats
    float* S2 = S1 + nS1;
    float* S  = S2 + nS1;                       // 10,314,304 floats
    float* part = S1;
    short* Ahi = (short*)S1;                    // 8*4*160320 = 5,130,240 shorts
    short* Alo = Ahi + (size_t)BB*CC*NPAD;      // total 10,260,480 shorts <= S1+S2 (10,314,304 short-equiv)
    short* Bts = (short*)d_out;                 // 245,760 shorts (= 122,880 floats)
    short* Bt  = (short*)((float*)d_out + 131072); // 225,280 shorts at float-offset 131072 (16B aligned)
    short* A  = (short*)S;                      // irfft A: 16016*704 bf16
    float* frames = S1;                         // 16016*320 floats over dead S1+S2

    int ngen = 2*FB*CC + 384*640 + NFFT*LDK;    // fused table generation
    k_gen<<<dim3((ngen + 255)/256), dim3(256), 0, stream>>>(win, htab, Bts, Bt);
    k_stats1<<<dim3(BB*RBLK), dim3(256), 0, stream>>>(in, part);
    k_stats2<<<dim3(BB), dim3(128), 0, stream>>>(part, mean, invmax);
    k_anorm<<<dim3((BB*CC*(NPAD/8) + 255)/256), dim3(256), 0, stream>>>(in, mean, invmax, Ahi, Alo);
    k_gstft<<<dim3(BB*TP*CC/64, 6), dim3(256), 0, stream>>>(Ahi, Alo, Bts, S);
    k_scan<<<dim3(2*BB*FB), dim3(256), 0, stream>>>(S, htab, S1, S2);
    k_pack<<<dim3(512), dim3(256), 0, stream>>>(S1, S2, A);
    k_gemm<<<dim3((GM + 63)/64, NFFT/64), dim3(256), 0, stream>>>(A, Bt, frames);
    k_ola<<<dim3((2*BB*(LL/4) + 255)/256), dim3(256), 0, stream>>>(frames, (float*)d_out);
}

// Round 17
// 221.360 us; speedup vs baseline: 1.1108x; 1.0132x over previous
//
#include <hip/hip_runtime.h>
#include <hip/hip_bf16.h>
#include <math.h>

#define BB 8
#define LL 160000
#define CC 4
#define NFFT 320
#define HOP 160
#define FB 161          // rfft bins
#define TT 1001         // frames
#define TP 1024         // padded frames per batch (t-slots) for STFT GEMM
#define RBLK 128        // stats blocks per batch
#define PI_D 3.14159265358979323846
#define NPAD 160320     // reflect-padded samples per (b,c): p in [-160, 160159]

#define CH 2            // scan t-chunk per thread (CH=2 + 256-thread blocks)
#define SCH 504         // scan outputs per half-block (2 halves cover 1001)
#define KWARM 4         // warm-up frames; tail weight 0.05^5 ~ 3e-7 rel << bf16 error floor (4.9e-4)

#define GM 16016        // irfft GEMM M = 2*BB*TT rows (beam,b,t)
#define KSEC 352        // irfft padded K per split-section (322 used)
#define LDK 704         // irfft A/Bt leading dim = 2 sections
#define KT 11           // irfft K-tiles of 32 per section
// NOTE: LDS row stride for bf16x8 tiles MUST keep rows 16B-aligned.
// stride 40 shorts = 80 B (aligned, ~2-way conflicts, cheap — R5: 61 us).
// stride 36 shorts = 72 B (misaligned b128 -> 3x slowdown — R9: 177 us). Do not repeat.
// LIFETIME NOTE (R13 bug): Bt/Bts must NOT live in the S region — k_gstft overwrites
// ALL of S. Both live in d_out's head (dead until k_ola fully overwrites at the end).

typedef __attribute__((ext_vector_type(8))) short bf16x8;
typedef __attribute__((ext_vector_type(4))) float f32x4;

__device__ __forceinline__ float2 cmulf(float2 a, float2 b){           // a*b
    return make_float2(a.x*b.x - a.y*b.y, a.x*b.y + a.y*b.x);
}
__device__ __forceinline__ float2 cmulcj(float2 a, float2 b){          // a*conj(b)
    return make_float2(a.x*b.x + a.y*b.y, a.y*b.x - a.x*b.y);
}
__device__ __forceinline__ float2 cjmul(float2 a, float2 b){           // conj(a)*b
    return make_float2(a.x*b.x + a.y*b.y, a.x*b.y - a.y*b.x);
}
__device__ __forceinline__ float2 csub(float2 a, float2 b){ return make_float2(a.x-b.x, a.y-b.y); }
__device__ __forceinline__ float2 cscale(float2 a, float s){ return make_float2(a.x*s, a.y*s); }
__device__ __forceinline__ float2 cdivf(float2 a, float2 b){           // a/b
    float inv = 1.0f/(b.x*b.x + b.y*b.y);
    return make_float2((a.x*b.x + a.y*b.y)*inv, (a.y*b.x - a.x*b.y)*inv);
}
__device__ __forceinline__ short bf_hi(float v){
    __hip_bfloat16 h = __float2bfloat16(v);
    short s; __builtin_memcpy(&s, &h, 2); return s;
}
__device__ __forceinline__ short bf_lo(float v){
    __hip_bfloat16 h = __float2bfloat16(v);
    float r = v - __bfloat162float(h);
    __hip_bfloat16 l = __float2bfloat16(r);
    short s; __builtin_memcpy(&s, &l, 2); return s;
}

// ---------- fused table generator: htab | Bts (STFT B) | Bt (irfft B) ----------
__global__ void k_gen(const float* __restrict__ win, float* __restrict__ htab,
                      short* __restrict__ Bts, short* __restrict__ Bt){
    int gid = blockIdx.x*256 + threadIdx.x;
    if (gid < 2*FB*CC){
        int i = gid;
        int c = i & 3;
        int k = (i >> 2) % FB;
        int m = i / (FB*CC);
        double coef = 2.0*PI_D*50.0*0.027*sin(40.0*PI_D/180.0)/340.0;
        double sgn = (m == 0) ? -1.0 : 1.0;
        double ph = sgn*coef*(double)k*(double)c;
        double s, c2;
        sincos(ph, &s, &c2);
        ((float2*)htab)[i] = make_float2((float)c2, (float)s);
        return;
    }
    gid -= 2*FB*CC;
    if (gid < 384*640){
        int col = gid / 640, kk = gid % 640;
        int n = (kk >= 320) ? kk - 320 : kk;
        int sec = (kk >= 320) ? 1 : 0;
        float v = 0.f;
        if (col < 2*FB){
            int k = col >> 1;
            double th = 2.0*PI_D*(double)k*(double)n/320.0;
            double s, co; sincos(th, &s, &co);
            double tw = (col & 1) ? -s : co;
            v = (float)((double)win[n]*tw);
        }
        Bts[gid] = sec ? bf_lo(v) : bf_hi(v);
        return;
    }
    gid -= 384*640;
    if (gid < NFFT*LDK){
        int n = gid / LDK, kk = gid % LDK;
        int sec = (kk >= KSEC) ? 1 : 0;
        int kk2 = kk - (sec ? KSEC : 0);
        float v = 0.f;
        if (kk2 < 2*FB){
            int bin = kk2 >> 1;
            double c = ((bin == 0 || bin == 160) ? 1.0 : 2.0) / 320.0;
            double th = 2.0*PI_D*(double)bin*(double)n/320.0;
            double s, co; sincos(th, &s, &co);
            v = (float)((kk2 & 1) ? -c*s : c*co);
        }
        Bt[(size_t)n*LDK + kk] = sec ? bf_lo(v) : bf_hi(v);
    }
}

// ---------- stage 1: per-(b,chunk) partial {sum4, min4, max4} ----------
__global__ __launch_bounds__(256) void k_stats1(const float* __restrict__ in, float* __restrict__ part){
    __shared__ float4 s4[256];
    __shared__ float4 mn4[256];
    __shared__ float4 mx4[256];
    int b = blockIdx.x / RBLK, chunk = blockIdx.x % RBLK;
    int tid = threadIdx.x;
    const float4* p = (const float4*)(in + (size_t)b*LL*CC);
    const int per = LL / RBLK;
    int start = chunk*per;
    float4 s  = make_float4(0.f,0.f,0.f,0.f);
    float4 mn = make_float4( 3.4e38f, 3.4e38f, 3.4e38f, 3.4e38f);
    float4 mx = make_float4(-3.4e38f,-3.4e38f,-3.4e38f,-3.4e38f);
    for (int i = start + tid; i < start + per; i += 256){
        float4 v = p[i];
        s.x += v.x; s.y += v.y; s.z += v.z; s.w += v.w;
        mn.x = fminf(mn.x, v.x); mn.y = fminf(mn.y, v.y); mn.z = fminf(mn.z, v.z); mn.w = fminf(mn.w, v.w);
        mx.x = fmaxf(mx.x, v.x); mx.y = fmaxf(mx.y, v.y); mx.z = fmaxf(mx.z, v.z); mx.w = fmaxf(mx.w, v.w);
    }
    s4[tid] = s; mn4[tid] = mn; mx4[tid] = mx;
    __syncthreads();
    for (int st = 128; st >= 1; st >>= 1){
        if (tid < st){
            float4 a = s4[tid], c = s4[tid+st];
            s4[tid] = make_float4(a.x+c.x, a.y+c.y, a.z+c.z, a.w+c.w);
            float4 d = mn4[tid], e = mn4[tid+st];
            mn4[tid] = make_float4(fminf(d.x,e.x), fminf(d.y,e.y), fminf(d.z,e.z), fminf(d.w,e.w));
            float4 f = mx4[tid], g = mx4[tid+st];
            mx4[tid] = make_float4(fmaxf(f.x,g.x), fmaxf(f.y,g.y), fmaxf(f.z,g.z), fmaxf(f.w,g.w));
        }
        __syncthreads();
    }
    if (tid == 0){
        float* dst = part + (size_t)(b*RBLK + chunk)*12;
        float4 a = s4[0], d = mn4[0], f = mx4[0];
        dst[0]=a.x; dst[1]=a.y; dst[2]=a.z; dst[3]=a.w;
        dst[4]=d.x; dst[5]=d.y; dst[6]=d.z; dst[7]=d.w;
        dst[8]=f.x; dst[9]=f.y; dst[10]=f.z; dst[11]=f.w;
    }
}

// ---------- stage 2: finalize mean + invmax per batch ----------
__global__ __launch_bounds__(128) void k_stats2(const float* __restrict__ part,
                                                float* __restrict__ mean, float* __restrict__ invmax){
    __shared__ float4 s4[128];
    __shared__ float4 mn4[128];
    __shared__ float4 mx4[128];
    int b = blockIdx.x, tid = threadIdx.x;
    const float* src = part + (size_t)(b*RBLK + tid)*12;
    s4[tid]  = make_float4(src[0], src[1], src[2], src[3]);
    mn4[tid] = make_float4(src[4], src[5], src[6], src[7]);
    mx4[tid] = make_float4(src[8], src[9], src[10], src[11]);
    __syncthreads();
    for (int st = 64; st >= 1; st >>= 1){
        if (tid < st){
            float4 a = s4[tid], c = s4[tid+st];
            s4[tid] = make_float4(a.x+c.x, a.y+c.y, a.z+c.z, a.w+c.w);
            float4 d = mn4[tid], e = mn4[tid+st];
            mn4[tid] = make_float4(fminf(d.x,e.x), fminf(d.y,e.y), fminf(d.z,e.z), fminf(d.w,e.w));
            float4 f = mx4[tid], g = mx4[tid+st];
            mx4[tid] = make_float4(fmaxf(f.x,g.x), fmaxf(f.y,g.y), fmaxf(f.z,g.z), fmaxf(f.w,g.w));
        }
        __syncthreads();
    }
    if (tid == 0){
        float4 sum = s4[0], mn = mn4[0], mx = mx4[0];
        float m0 = sum.x*(1.0f/LL), m1 = sum.y*(1.0f/LL), m2 = sum.z*(1.0f/LL), m3 = sum.w*(1.0f/LL);
        mean[b*4+0]=m0; mean[b*4+1]=m1; mean[b*4+2]=m2; mean[b*4+3]=m3;
        float a0 = fmaxf(mx.x - m0, m0 - mn.x);
        float a1 = fmaxf(mx.y - m1, m1 - mn.y);
        float a2 = fmaxf(mx.z - m2, m2 - mn.z);
        float a3 = fmaxf(mx.w - m3, m3 - mn.w);
        invmax[b] = 1.0f / fmaxf(fmaxf(a0, a1), fmaxf(a2, a3));
    }
}

// ---------- A-normalize: reflect-padded normalized bf16 hi/lo planes Ahi/Alo[b][c][NPAD] ----------
__global__ __launch_bounds__(256) void k_anorm(const float* __restrict__ in,
        const float* __restrict__ mean, const float* __restrict__ invmax,
        short* __restrict__ Ahi, short* __restrict__ Alo){
    int gid = blockIdx.x*256 + threadIdx.x;
    if (gid >= BB*CC*(NPAD/8)) return;
    int p8 = gid % (NPAD/8);
    int bc = gid / (NPAD/8);
    int b = bc >> 2;
    float mc = mean[bc];
    float iv = invmax[b];
    const float* px = in + (size_t)b*LL*CC + (bc & 3);
    bf16x8 h8, l8;
    #pragma unroll
    for (int j = 0; j < 8; ++j){
        int p = p8*8 + j - 160;
        int m2 = p < 0 ? -p : (p >= LL ? 2*LL - 2 - p : p);
        float v = (px[(size_t)m2*CC] - mc) * iv;
        __hip_bfloat16 h = __float2bfloat16(v);
        float r = v - __bfloat162float(h);
        __hip_bfloat16 l = __float2bfloat16(r);
        short hs, ls; __builtin_memcpy(&hs, &h, 2); __builtin_memcpy(&ls, &l, 2);
        h8[j] = hs; l8[j] = ls;
    }
    size_t o = (size_t)bc*NPAD + (size_t)p8*8;
    *(bf16x8*)&Ahi[o] = h8;
    *(bf16x8*)&Alo[o] = l8;
}

// ---------- STFT as MFMA GEMM (R5 structure, precomputed A planes): rows=(b,t,c), cols=(k,ri) ----------
// S out layout: complex S[b][k][t][c], c fastest (two float4 per (b,k,t))
__global__ __launch_bounds__(256) void k_gstft(const short* __restrict__ Ahi, const short* __restrict__ Alo,
        const short* __restrict__ Bts, float* __restrict__ S){
    __shared__ short stage[4*2560];          // Ah|Al|Bh|Bl, rows stride 40 shorts (80B, 16B-aligned)
    short* Ah = stage;
    short* Al = stage + 2560;
    short* Bh = stage + 5120;
    short* Bl = stage + 7680;
    float* Ct = (float*)stage;               // 64 x 66 floats (16.9 KB) overlays after K-loop
    int tid = threadIdx.x;
    int row0 = blockIdx.x*64;                // over b*TP*CC rows
    int col0 = blockIdx.y*64;
    int b  = row0 >> 12;                     // TP*CC = 4096 rows per batch
    int t0 = (row0 & 4095) >> 2;
    int tr = tid >> 2, tq = tid & 3, tk = tq*8;
    int tloc = t0 + (tr >> 2);
    int c    = tr & 3;
    bool vt  = tloc < TT;
    const short* pah = Ahi + (size_t)(b*4 + c)*NPAD;
    const short* pal = Alo + (size_t)(b*4 + c)*NPAD;
    int npbase = tloc*160;                   // p = tloc*HOP - HOP + n  ->  np = p + 160 = tloc*160 + n
    int wave = tid >> 6, lane = tid & 63;
    int wm = wave >> 1, wn = wave & 1;
    int l15 = lane & 15, quad = lane >> 4;
    f32x4 acc00 = {0.f,0.f,0.f,0.f}, acc01 = acc00, acc10 = acc00, acc11 = acc00;
    for (int kt = 0; kt < 10; ++kt){
        int k0 = kt*32;
        __syncthreads();
        bf16x8 hv = {}, lv = {};
        if (vt){
            hv = *(const bf16x8*)&pah[npbase + k0 + tk];
            lv = *(const bf16x8*)&pal[npbase + k0 + tk];
        }
        *(bf16x8*)&Ah[tr*40 + tk] = hv;
        *(bf16x8*)&Al[tr*40 + tk] = lv;
        const short* bp = Bts + (size_t)(col0 + tr)*640 + k0 + tk;
        *(bf16x8*)&Bh[tr*40 + tk] = *(const bf16x8*)bp;
        *(bf16x8*)&Bl[tr*40 + tk] = *(const bf16x8*)(bp + 320);
        __syncthreads();
        bf16x8 a0h = *(bf16x8*)&Ah[(wm*32 + l15)*40 + quad*8];
        bf16x8 a1h = *(bf16x8*)&Ah[(wm*32 + 16 + l15)*40 + quad*8];
        bf16x8 a0l = *(bf16x8*)&Al[(wm*32 + l15)*40 + quad*8];
        bf16x8 a1l = *(bf16x8*)&Al[(wm*32 + 16 + l15)*40 + quad*8];
        bf16x8 b0h = *(bf16x8*)&Bh[(wn*32 + l15)*40 + quad*8];
        bf16x8 b1h = *(bf16x8*)&Bh[(wn*32 + 16 + l15)*40 + quad*8];
        bf16x8 b0l = *(bf16x8*)&Bl[(wn*32 + l15)*40 + quad*8];
        bf16x8 b1l = *(bf16x8*)&Bl[(wn*32 + 16 + l15)*40 + quad*8];
        acc00 = __builtin_amdgcn_mfma_f32_16x16x32_bf16(a0h, b0h, acc00, 0, 0, 0);
        acc01 = __builtin_amdgcn_mfma_f32_16x16x32_bf16(a0h, b1h, acc01, 0, 0, 0);
        acc10 = __builtin_amdgcn_mfma_f32_16x16x32_bf16(a1h, b0h, acc10, 0, 0, 0);
        acc11 = __builtin_amdgcn_mfma_f32_16x16x32_bf16(a1h, b1h, acc11, 0, 0, 0);
        acc00 = __builtin_amdgcn_mfma_f32_16x16x32_bf16(a0l, b0h, acc00, 0, 0, 0);
        acc01 = __builtin_amdgcn_mfma_f32_16x16x32_bf16(a0l, b1h, acc01, 0, 0, 0);
        acc10 = __builtin_amdgcn_mfma_f32_16x16x32_bf16(a1l, b0h, acc10, 0, 0, 0);
        acc11 = __builtin_amdgcn_mfma_f32_16x16x32_bf16(a1l, b1h, acc11, 0, 0, 0);
        acc00 = __builtin_amdgcn_mfma_f32_16x16x32_bf16(a0h, b0l, acc00, 0, 0, 0);
        acc01 = __builtin_amdgcn_mfma_f32_16x16x32_bf16(a0h, b1l, acc01, 0, 0, 0);
        acc10 = __builtin_amdgcn_mfma_f32_16x16x32_bf16(a1h, b0l, acc10, 0, 0, 0);
        acc11 = __builtin_amdgcn_mfma_f32_16x16x32_bf16(a1h, b1l, acc11, 0, 0, 0);
    }
    // epilogue: LDS transpose, out in S layout
    __syncthreads();                       // staging reads done; Ct overlays
    #pragma unroll
    for (int r = 0; r < 4; ++r){
        int rl = wm*32 + quad*4 + r;       // channel = r (rl & 3 == r)
        Ct[rl*66 + wn*32 + l15]           = acc00[r];
        Ct[rl*66 + wn*32 + l15 + 16]      = acc01[r];
        Ct[(rl+16)*66 + wn*32 + l15]      = acc10[r];
        Ct[(rl+16)*66 + wn*32 + l15 + 16] = acc11[r];
    }
    __syncthreads();
    int tl = tid & 15, h = (tid >> 4) & 1, kq = tid >> 5;
    int t = t0 + tl;
    if (t < TT){
        float4* S4 = (float4*)S;
        for (int kk = kq; kk < 32; kk += 8){
            int kg = (col0 >> 1) + kk;
            if (kg < FB){
                float2 e0 = *(float2*)&Ct[(tl*4 + 2*h)*66 + 2*kk];
                float2 e1 = *(float2*)&Ct[(tl*4 + 2*h + 1)*66 + 2*kk];
                S4[((size_t)(b*FB + kg)*TT + t)*2 + h] = make_float4(e0.x, e0.y, e1.x, e1.y);
            }
        }
    }
}

// covariance recurrence update: R = a*R + wg*outer(X), a/wg handle first-frame
#define UPD(first) do{ \
    float aa = (first) ? 0.f : 0.05f; float wg = (first) ? 1.f : 0.95f; \
    float y0x=wg*x0.x, y0y=wg*x0.y, y1x=wg*x1.x, y1y=wg*x1.y; \
    float y2x=wg*x2.x, y2y=wg*x2.y, y3x=wg*x3.x, y3y=wg*x3.y; \
    d0 = aa*d0 + y0x*x0.x + y0y*x0.y; \
    d1 = aa*d1 + y1x*x1.x + y1y*x1.y; \
    d2 = aa*d2 + y2x*x2.x + y2y*x2.y; \
    d3 = aa*d3 + y3x*x3.x + y3y*x3.y; \
    r10.x = aa*r10.x + y1x*x0.x + y1y*x0.y;  r10.y = aa*r10.y + y1y*x0.x - y1x*x0.y; \
    r20.x = aa*r20.x + y2x*x0.x + y2y*x0.y;  r20.y = aa*r20.y + y2y*x0.x - y2x*x0.y; \
    r30.x = aa*r30.x + y3x*x0.x + y3y*x0.y;  r30.y = aa*r30.y + y3y*x0.x - y3x*x0.y; \
    r21.x = aa*r21.x + y2x*x1.x + y2y*x1.y;  r21.y = aa*r21.y + y2y*x1.x - y2x*x1.y; \
    r31.x = aa*r31.x + y3x*x1.x + y3y*x1.y;  r31.y = aa*r31.y + y3y*x1.x - y3x*x1.y; \
    r32.x = aa*r32.x + y3x*x2.x + y3y*x2.y;  r32.y = aa*r32.y + y3y*x2.x - y3x*x2.y; \
}while(0)

// ---------- LDS-staged chunked scan, half-strip, CH=2 x 256 threads, 4-frame warm-up ----------
// Warm-up frames below tbase (threads 0..1) come straight from gmem.
// Division/sqrt-free Schur-adjugate solve (scale-invariance of s). S1/S2 layout: complex [b][f][t]
__global__ __launch_bounds__(256) void k_scan(const float* __restrict__ S, const float* __restrict__ htab,
                      float* __restrict__ S1, float* __restrict__ S2){
    __shared__ float4 tile[1008];     // 16,128 B: swizzled [tbase,te) strip; reused as output buffer
    int bid = blockIdx.x;
    int half = bid & 1;
    int bf = bid >> 1;                // b*FB + f
    int f  = bf % FB;
    int tid = threadIdx.x;
    int tbase = half*SCH;
    int te  = tbase + SCH; if (te > TT) te = TT;
    int nst = 2*(te - tbase);
    const float4* Sg = (const float4*)S + (size_t)bf*TT*2;
    const float4* Sp = Sg + (size_t)tbase*2;
    for (int i = tid; i < nst; i += 256)
        tile[i ^ ((i>>4)&7)] = Sp[i];                    // coalesced gmem read, swizzled LDS write
    __syncthreads();
    float2 out1[CH], out2[CH];
    int t0 = tbase + tid*CH;
    bool act = (tid*CH < SCH) && (t0 < TT);
    if (act){
        const float2* hp = (const float2*)htab;
        float2 ha0 = hp[f*4+0], ha1 = hp[f*4+1], ha2 = hp[f*4+2], ha3 = hp[f*4+3];
        float2 hb0 = hp[(FB+f)*4+0], hb1 = hp[(FB+f)*4+1], hb2 = hp[(FB+f)*4+2], hb3 = hp[(FB+f)*4+3];
        float d0=0,d1=0,d2=0,d3=0;
        float2 r10={0,0}, r20={0,0}, r30={0,0}, r21={0,0}, r31={0,0}, r32={0,0};
        int ts = t0 - KWARM; if (ts < 0) ts = 0;
        for (int tau = ts; tau < t0; ++tau){
            float4 v0, v1;
            if (tau >= tbase){
                int i0 = 2*(tau - tbase);
                v0 = tile[i0 ^ ((i0>>4)&7)];
                v1 = tile[(i0+1) ^ ((i0>>4)&7)];
            } else {
                v0 = Sg[2*tau];
                v1 = Sg[2*tau + 1];
            }
            float2 x0 = make_float2(v0.x, v0.y), x1 = make_float2(v0.z, v0.w);
            float2 x2 = make_float2(v1.x, v1.y), x3 = make_float2(v1.z, v1.w);
            UPD(tau == 0);
        }
        for (int j = 0; j < CH; ++j){
            int t = t0 + j;
            if (t >= TT) break;
            int i0 = 2*(t - tbase);
            float4 v0 = tile[i0 ^ ((i0>>4)&7)];
            float4 v1 = tile[(i0+1) ^ ((i0>>4)&7)];
            float2 x0 = make_float2(v0.x, v0.y), x1 = make_float2(v0.z, v0.w);
            float2 x2 = make_float2(v1.x, v1.y), x3 = make_float2(v1.z, v1.w);
            UPD(t == 0);
            float trc = d0 + d1 + d2 + d3;
            float lam = trc * 0.25f;
            float e0 = d0 + lam, e1 = d1 + lam, e2 = d2 + lam, e3 = d3 + lam;
            float detP = e0*e1 - (r10.x*r10.x + r10.y*r10.y);
            float2 w00 = csub(cscale(r20, e1), cmulf(r10, r21));
            float2 w01 = csub(cscale(r30, e1), cmulf(r10, r31));
            float2 w10 = csub(cscale(r21, e0), cjmul(r10, r20));
            float2 w11 = csub(cscale(r31, e0), cjmul(r10, r30));
            float2 va = cjmul(r30, w00), vb = cjmul(r31, w10);
            float2 V10 = make_float2(va.x + vb.x, -(va.y + vb.y));
            float reV00 = r20.x*w00.x + r20.y*w00.y + r21.x*w10.x + r21.y*w10.y;
            float reV11 = r30.x*w01.x + r30.y*w01.y + r31.x*w11.x + r31.y*w11.y;
            float t00 = detP*e2 - reV00;
            float t11 = detP*e3 - reV11;
            float2 t10 = csub(cscale(r32, detP), V10);
            float detT = t00*t11 - (t10.x*t10.x + t10.y*t10.y);
            #pragma unroll
            for (int m = 0; m < 2; ++m){
                float2 h0 = m ? hb0 : ha0;
                float2 h1 = m ? hb1 : ha1;
                float2 h2 = m ? hb2 : ha2;
                float2 h3 = m ? hb3 : ha3;
                float2 g0 = csub(cscale(h0, e1), cjmul(r10, h1));
                float2 g1 = csub(cscale(h1, e0), cmulf(r10, h0));
                float2 ta = cmulf(r20, g0), tb = cmulf(r21, g1);
                float2 hh0 = make_float2(detP*h2.x - ta.x - tb.x, detP*h2.y - ta.y - tb.y);
                ta = cmulf(r30, g0); tb = cmulf(r31, g1);
                float2 hh1 = make_float2(detP*h3.x - ta.x - tb.x, detP*h3.y - ta.y - tb.y);
                float2 y20 = csub(cscale(hh0, t11), cjmul(t10, hh1));
                float2 y21 = csub(cscale(hh1, t00), cmulf(t10, hh0));
                float2 u20 = cscale(y20, detP), u21 = cscale(y21, detP);
                ta = cmulcj(y20, r20); tb = cmulcj(y21, r30);
                float2 q0 = make_float2(detT*h0.x - ta.x - tb.x, detT*h0.y - ta.y - tb.y);
                ta = cmulcj(y20, r21); tb = cmulcj(y21, r31);
                float2 q1 = make_float2(detT*h1.x - ta.x - tb.x, detT*h1.y - ta.y - tb.y);
                float2 u10 = csub(cscale(q0, e1), cjmul(r10, q1));
                float2 u11 = csub(cscale(q1, e0), cmulf(r10, q0));
                float2 den = cjmul(h0, u10), tmp;
                tmp = cjmul(h1, u11); den.x += tmp.x; den.y += tmp.y;
                tmp = cjmul(h2, u20); den.x += tmp.x; den.y += tmp.y;
                tmp = cjmul(h3, u21); den.x += tmp.x; den.y += tmp.y;
                float2 num = cjmul(u10, x0);
                tmp = cjmul(u11, x1); num.x += tmp.x; num.y += tmp.y;
                tmp = cjmul(u20, x2); num.x += tmp.x; num.y += tmp.y;
                tmp = cjmul(u21, x3); num.x += tmp.x; num.y += tmp.y;
                float2 s = cdivf(num, make_float2(den.x, -den.y));
                if (m) out2[j] = s; else out1[j] = s;
            }
        }
    }
    __syncthreads();                      // all tile reads done -> reuse as output buffers
    float2* o1 = (float2*)tile;           // [0..511]
    float2* o2 = ((float2*)tile) + 528;   // [528..1039] (ends at float4 520 <= 1008)
    if (act){
        for (int j = 0; j < CH && t0 + j < TT; ++j){
            int lt = t0 - tbase + j;
            int iw = lt ^ ((lt>>3)&7);    // bank-spread write
            o1[iw] = out1[j];
            o2[iw] = out2[j];
        }
    }
    __syncthreads();
    int nout = te - tbase;
    float2* S1g = (float2*)S1 + (size_t)bf*TT + tbase;
    float2* S2g = (float2*)S2 + (size_t)bf*TT + tbase;
    for (int i = tid; i < nout; i += 256){
        int ir = i ^ ((i>>3)&7);
        S1g[i] = o1[ir];
        S2g[i] = o2[ir];
    }
}

// ---------- pack v2 (R8-verified): coalesced LDS transpose. block = (rb, 32-t tile) ----------
__global__ __launch_bounds__(256) void k_pack(const float* __restrict__ S1, const float* __restrict__ S2,
                                              short* __restrict__ A){
    __shared__ short tile[32*708];        // 45,312 B; row = t-in-tile, col = kk (hi 0..351 | lo 352..703)
    int bid = blockIdx.x;                 // rb*32 + tb
    int tb = bid & 31, rb = bid >> 5;
    int t0 = tb*32;
    int beam = rb >> 3, b = rb & 7;
    const float2* Sp = (const float2*)(beam ? S2 : S1) + (size_t)b*FB*TT;
    int tid = threadIdx.x;
    for (int idx = tid; idx < 32*176; idx += 256){
        int bin = idx >> 5, tq = idx & 31;
        int t = t0 + tq;
        float2 s = make_float2(0.f, 0.f);
        if (bin < FB && t < TT) s = Sp[(size_t)bin*TT + t];
        int c0 = 2*bin;
        tile[tq*708 + c0]            = bf_hi(s.x);
        tile[tq*708 + c0 + 1]        = bf_hi(s.y);
        tile[tq*708 + KSEC + c0]     = bf_lo(s.x);
        tile[tq*708 + KSEC + c0 + 1] = bf_lo(s.y);
    }
    __syncthreads();
    for (int idx = tid; idx < 32*176; idx += 256){
        int tq = idx / 176, k4 = idx % 176;
        int t = t0 + tq;
        if (t < TT)
            *(short4*)&A[(size_t)(rb*TT + t)*LDK + k4*4] = *(short4*)&tile[tq*708 + k4*4];
    }
}

// ---------- irfft MFMA GEMM: frames[GM,320] = 3-segment bf16 split product ----------
__global__ __launch_bounds__(256) void k_gemm(const short* __restrict__ A, const short* __restrict__ Bt,
                                              float* __restrict__ C){
    __shared__ short As[64*40];
    __shared__ short Bs[64*40];
    int tid = threadIdx.x;
    int row0 = blockIdx.x * 64;
    int col0 = blockIdx.y * 64;
    int wave = tid >> 6, lane = tid & 63;
    int wm = wave >> 1, wn = wave & 1;
    int l15 = lane & 15, quad = lane >> 4;
    f32x4 acc00 = {0.f,0.f,0.f,0.f}, acc01 = acc00, acc10 = acc00, acc11 = acc00;
    int tr = tid >> 2;
    int tk = (tid & 3) * 8;
    int gr = row0 + tr;
    bool rok = gr < GM;
    const size_t arow = (size_t)gr*LDK;
    const size_t brow = (size_t)(col0 + tr)*LDK;
    for (int seg = 0; seg < 3; ++seg){
        int aofs = (seg == 1) ? KSEC : 0;
        int bofs = (seg == 2) ? KSEC : 0;
        for (int kt = 0; kt < KT; ++kt){
            int k0 = kt*32;
            __syncthreads();
            bf16x8 av = {};
            if (rok) av = *(const bf16x8*)&A[arow + aofs + k0 + tk];
            bf16x8 bv = *(const bf16x8*)&Bt[brow + bofs + k0 + tk];
            *(bf16x8*)&As[tr*40 + tk] = av;
            *(bf16x8*)&Bs[tr*40 + tk] = bv;
            __syncthreads();
            bf16x8 a0 = *(bf16x8*)&As[(wm*32 + l15)*40 + quad*8];
            bf16x8 a1 = *(bf16x8*)&As[(wm*32 + 16 + l15)*40 + quad*8];
            bf16x8 b0 = *(bf16x8*)&Bs[(wn*32 + l15)*40 + quad*8];
            bf16x8 b1 = *(bf16x8*)&Bs[(wn*32 + 16 + l15)*40 + quad*8];
            acc00 = __builtin_amdgcn_mfma_f32_16x16x32_bf16(a0, b0, acc00, 0, 0, 0);
            acc01 = __builtin_amdgcn_mfma_f32_16x16x32_bf16(a0, b1, acc01, 0, 0, 0);
            acc10 = __builtin_amdgcn_mfma_f32_16x16x32_bf16(a1, b0, acc10, 0, 0, 0);
            acc11 = __builtin_amdgcn_mfma_f32_16x16x32_bf16(a1, b1, acc11, 0, 0, 0);
        }
    }
    for (int r = 0; r < 4; ++r){
        int orow0 = row0 + wm*32 + quad*4 + r;
        int ocol0 = col0 + wn*32 + l15;
        if (orow0 < GM){
            C[(size_t)orow0*NFFT + ocol0]      = acc00[r];
            C[(size_t)orow0*NFFT + ocol0 + 16] = acc01[r];
        }
        if (orow0 + 16 < GM){
            C[(size_t)(orow0+16)*NFFT + ocol0]      = acc10[r];
            C[(size_t)(orow0+16)*NFFT + ocol0 + 16] = acc11[r];
        }
    }
}

// ---------- overlap-add, float4: 4 outputs/thread (wsum==2 in cropped interior) ----------
__global__ __launch_bounds__(256) void k_ola(const float* __restrict__ frames, float* __restrict__ out){
    int gid = blockIdx.x*256 + threadIdx.x;
    if (gid >= 2*BB*(LL/4)) return;
    int o4 = (gid % (LL/4))*4;
    int rb = gid / (LL/4);                 // beam*BB + b
    int i  = o4 + HOP;                     // mult of 4; r in {0,4,...,156}
    int t1 = i / HOP;
    int r  = i - t1*HOP;
    const float4* fb = (const float4*)(frames + (size_t)rb*TT*NFFT);
    float4 a = fb[(t1*NFFT + r) >> 2];
    float4 b = fb[((t1-1)*NFFT + r + HOP) >> 2];
    ((float4*)out)[gid] = make_float4(0.5f*(a.x+b.x), 0.5f*(a.y+b.y), 0.5f*(a.z+b.z), 0.5f*(a.w+b.w));
}

extern "C" void kernel_launch(void* const* d_in, const int* in_sizes, int n_in,
                              void* d_out, int out_size, void* d_ws, size_t ws_size,
                              hipStream_t stream){
    const float* in  = (const float*)d_in[0];   // [B, L, C] fp32
    const float* win = (const float*)d_in[1];   // [320] fp32
    float* ws = (float*)d_ws;
    // ws (floats): mean 32 | invmax 8 | htab 2576 | pad -> header 3072
    //              | S1 (2,578,576) | S2 (2,578,576) | S (10,314,304)   total ~62 MB
    // aliases: part -> S1 head (dead before k_anorm); Ahi/Alo -> S1+S2 (dead after k_gstft);
    //          Bts + Bt -> head of d_out (dead until k_ola fully overwrites; NOT in S — R13 bug);
    //          A_ir -> S (post-scan); frames -> S1/S2 (post-pack)
    float* mean   = ws;
    float* invmax = ws + 32;
    float* htab   = ws + 48;
    float* S1     = ws + 3072;
    size_t nS1 = (size_t)2*BB*FB*TT;            // 2,578,576 floats
    float* S2 = S1 + nS1;
    float* S  = S2 + nS1;                       // 10,314,304 floats
    float* part = S1;
    short* Ahi = (short*)S1;                    // 8*4*160320 = 5,130,240 shorts
    short* Alo = Ahi + (size_t)BB*CC*NPAD;      // total 10,260,480 shorts <= S1+S2 (10,314,304 short-equiv)
    short* Bts = (short*)d_out;                 // 245,760 shorts (= 122,880 floats)
    short* Bt  = (short*)((float*)d_out + 131072); // 225,280 shorts at float-offset 131072 (16B aligned)
    short* A  = (short*)S;                      // irfft A: 16016*704 bf16
    float* frames = S1;                         // 16016*320 floats over dead S1+S2

    int ngen = 2*FB*CC + 384*640 + NFFT*LDK;    // fused table generation
    k_gen<<<dim3((ngen + 255)/256), dim3(256), 0, stream>>>(win, htab, Bts, Bt);
    k_stats1<<<dim3(BB*RBLK), dim3(256), 0, stream>>>(in, part);
    k_stats2<<<dim3(BB), dim3(128), 0, stream>>>(part, mean, invmax);
    k_anorm<<<dim3((BB*CC*(NPAD/8) + 255)/256), dim3(256), 0, stream>>>(in, mean, invmax, Ahi, Alo);
    k_gstft<<<dim3(BB*TP*CC/64, 6), dim3(256), 0, stream>>>(Ahi, Alo, Bts, S);
    k_scan<<<dim3(2*BB*FB), dim3(256), 0, stream>>>(S, htab, S1, S2);
    k_pack<<<dim3(512), dim3(256), 0, stream>>>(S1, S2, A);
    k_gemm<<<dim3((GM + 63)/64, NFFT/64), dim3(256), 0, stream>>>(A, Bt, frames);
    k_ola<<<dim3((2*BB*(LL/4) + 255)/256), dim3(256), 0, stream>>>(frames, (float*)d_out);
}